// Round 3
// baseline (2393.786 us; speedup 1.0000x reference)
//
#include <hip/hip_runtime.h>
#include <hip/hip_bf16.h>

using bf16 = __hip_bfloat16;

#define Bc 8
#define Tc 12
#define Nc 512
#define Dc 128
#define T_Hc 2
#define GEO_Hc 4
#define SEM_Hc 2
#define HDc 16
#define SCALEc 0.25f

// ================= ws layout =================
// bf16 region (offsets in halves) for all large intermediates
constexpr size_t TSZ = (size_t)Bc * Nc * T_Hc * Tc * HDc;      // 1,572,864
constexpr size_t GSZ = (size_t)Bc * Tc * GEO_Hc * Nc * HDc;    // 3,145,728
constexpr size_t SSZ = (size_t)Bc * Tc * SEM_Hc * Nc * HDc;    // 1,572,864
constexpr size_t CSZ = (size_t)Bc * Tc * Nc * Dc;              // 6,291,456
constexpr size_t H_TQ = 0;
constexpr size_t H_TK = H_TQ + TSZ;
constexpr size_t H_TV = H_TK + TSZ;
constexpr size_t H_GQ = H_TV + TSZ;
constexpr size_t H_GK = H_GQ + GSZ;
constexpr size_t H_GV = H_GK + GSZ;
constexpr size_t H_SQ = H_GV + GSZ;
constexpr size_t H_SK = H_SQ + SSZ;
constexpr size_t H_SV = H_SK + SSZ;
constexpr size_t H_CC = H_SV + SSZ;
constexpr size_t H_END = H_CC + CSZ;                           // 25,165,824 halves
// fp32 region after the bf16 region (offsets in floats from ws base)
constexpr size_t F_PK = (H_END + 1) / 2;                       // 12,582,912
constexpr size_t F_PV = F_PK + 1024;
constexpr size_t F_FLAG = F_PV + 1024;                         // [0] = mask mode
// total ws need: ~50.34 MB

__device__ __forceinline__ float b2f(bf16 v) { return __bfloat162float(v); }
__device__ __forceinline__ bf16 f2b(float v) { return __float2bfloat16(v); }

// dot of a 128-wide fp32 weight row (global) with a 128-wide fp32 vector (LDS)
__device__ __forceinline__ float dotw128f(const float* __restrict__ w,
                                          const float* __restrict__ xr) {
    const float4* w4 = reinterpret_cast<const float4*>(w);
    float acc = 0.f;
#pragma unroll
    for (int j = 0; j < 32; ++j) {
        float4 a = w4[j];
        acc = fmaf(a.x, xr[4 * j], acc);
        acc = fmaf(a.y, xr[4 * j + 1], acc);
        acc = fmaf(a.z, xr[4 * j + 2], acc);
        acc = fmaf(a.w, xr[4 * j + 3], acc);
    }
    return acc;
}

// ---- kernel 0: pattern k/v projection + mask dtype detection --------------
__global__ __launch_bounds__(256) void k_prep(
    const float* __restrict__ pattern_keys, const float* __restrict__ pat_kw,
    const float* __restrict__ pat_kb, const float* __restrict__ pat_vw,
    const float* __restrict__ pat_vb, const unsigned char* __restrict__ mask,
    float* __restrict__ fws) {
    int tid = threadIdx.x;
    for (int idx = tid; idx < 2048; idx += 256) {
        int which = idx >> 10;           // 0 = pk, 1 = pv
        int r = idx & 1023;
        int k = r >> 6, e = r & 63;
        const float* w = (which ? pat_vw : pat_kw) + (size_t)e * 128;
        const float* pkey = pattern_keys + (size_t)k * 128;
        float acc = which ? pat_vb[e] : pat_kb[e];
        for (int d = 0; d < 128; ++d) acc = fmaf(pkey[d], w[d], acc);
        fws[(which ? F_PV : F_PK) + (size_t)k * 64 + e] = acc;
    }
    // mask storage detection over first 4096 bytes:
    //   u8:   nonzero bytes at offsets not ≡ 0 (mod 4)
    //   i32:  nonzero only at offsets ≡ 0 (mod 4), incl. ≡ 4 (mod 8)
    //   i64:  nonzero only at offsets ≡ 0 (mod 8)
    __shared__ int s_u8, s_odd4;
    if (tid == 0) { s_u8 = 0; s_odd4 = 0; }
    __syncthreads();
    int u8 = 0, odd4 = 0;
    for (int i = tid * 16; i < tid * 16 + 16; ++i) {
        unsigned char v = mask[i];
        if (v && (i & 3)) u8 = 1;
        if (v && ((i & 7) == 4)) odd4 = 1;
    }
    if (u8) atomicOr(&s_u8, 1);
    if (odd4) atomicOr(&s_odd4, 1);
    __syncthreads();
    if (tid == 0) fws[F_FLAG] = s_u8 ? 0.f : (s_odd4 ? 1.f : 2.f);
}

// ---- kernel 1: all projections + pattern attention ------------------------
__global__ __launch_bounds__(256) void k_proj(
    const float* __restrict__ x, const float* __restrict__ xp,
    const float* __restrict__ t_qw, const float* __restrict__ t_kw,
    const float* __restrict__ t_vw, const float* __restrict__ geo_qw,
    const float* __restrict__ geo_kw, const float* __restrict__ geo_vw,
    const float* __restrict__ sem_qw, const float* __restrict__ sem_kw,
    const float* __restrict__ sem_vw, const float* __restrict__ pat_qw,
    const float* __restrict__ pat_qb, bf16* __restrict__ hb,
    const float* __restrict__ fws) {
    __shared__ float xs[16 * 128];
    __shared__ float xps[16 * 128];
    __shared__ float pqs[16 * 64];
    __shared__ float gkbs[16 * 64];
    __shared__ float plog[16 * 16];

    int tid = threadIdx.x;
    size_t g0 = (size_t)blockIdx.x * 16;

    for (int u = tid; u < 2048; u += 256) {
        xs[u] = x[g0 * 128 + u];
        xps[u] = xp[g0 * 128 + u];
    }
    __syncthreads();

    for (int idx = tid; idx < 16 * 448; idx += 256) {
        int i = idx / 448;
        int c = idx - i * 448;
        size_t token = g0 + i;
        int b = (int)(token / (Tc * Nc));
        int rr0 = (int)(token - (size_t)b * Tc * Nc);
        int t = rr0 / Nc;
        int n = rr0 - t * Nc;
        const float* xr = xs + i * 128;

        if (c < 96) {                       // temporal q/k/v
            int which = c >> 5, cc = c & 31;
            int h = cc >> 4, d = cc & 15;
            const float* w = (which == 0 ? t_qw : which == 1 ? t_kw : t_vw) + (size_t)cc * 128;
            float v = dotw128f(w, xr);
            size_t base = (which == 0 ? H_TQ : which == 1 ? H_TK : H_TV);
            hb[base + ((size_t)(b * Nc + n) * T_Hc + h) * (Tc * HDc) + t * HDc + d] = f2b(v);
        } else if (c < 160) {               // geo q
            int r = c - 96;
            float v = dotw128f(geo_qw + (size_t)r * 128, xr);
            hb[H_GQ + ((((size_t)b * Tc + t) * GEO_Hc + (r >> 4)) * Nc + n) * HDc + (r & 15)] = f2b(v);
        } else if (c < 224) {               // geo k base (pattern added below)
            int r = c - 160;
            gkbs[i * 64 + r] = dotw128f(geo_kw + (size_t)r * 128, xr);
        } else if (c < 288) {               // geo v
            int r = c - 224;
            float v = dotw128f(geo_vw + (size_t)r * 128, xr);
            hb[H_GV + ((((size_t)b * Tc + t) * GEO_Hc + (r >> 4)) * Nc + n) * HDc + (r & 15)] = f2b(v);
        } else if (c < 384) {               // sem q/k/v
            int cc = c - 288;
            int which = cc >> 5, r = cc & 31;
            const float* w = (which == 0 ? sem_qw : which == 1 ? sem_kw : sem_vw) + (size_t)r * 128;
            float v = dotw128f(w, xr);
            size_t base = (which == 0 ? H_SQ : which == 1 ? H_SK : H_SV);
            hb[base + ((((size_t)b * Tc + t) * SEM_Hc + (r >> 4)) * Nc + n) * HDc + (r & 15)] = f2b(v);
        } else {                            // pattern q (from x_patterns) + bias
            int r = c - 384;
            pqs[i * 64 + r] = dotw128f(pat_qw + (size_t)r * 128, xps + i * 128) + pat_qb[r];
        }
    }
    __syncthreads();

    {   // pattern logits: thread (i,k)
        int i = tid >> 4, k = tid & 15;
        const float* pkrow = fws + F_PK + (size_t)k * 64;
        const float* pqrow = pqs + i * 64;
        float acc = 0.f;
#pragma unroll 16
        for (int e = 0; e < 64; ++e) acc = fmaf(pqrow[e], pkrow[e], acc);
        plog[i * 16 + k] = acc * SCALEc;
    }
    __syncthreads();

    {   // softmax over K=16 + geo_k finalize: thread (i,j) does channels 4j..4j+3
        int i = tid >> 4, j = tid & 15;
        size_t token = g0 + i;
        int b = (int)(token / (Tc * Nc));
        int rr0 = (int)(token - (size_t)b * Tc * Nc);
        int t = rr0 / Nc;
        int n = rr0 - t * Nc;
        float mx = -1e30f;
        for (int k = 0; k < 16; ++k) mx = fmaxf(mx, plog[i * 16 + k]);
        float p[16];
        float sum = 0.f;
        for (int k = 0; k < 16; ++k) {
            p[k] = __expf(plog[i * 16 + k] - mx);
            sum += p[k];
        }
        float inv = 1.f / sum;
        for (int cd = 0; cd < 4; ++cd) {
            int c = j * 4 + cd;
            float acc = 0.f;
            for (int k = 0; k < 16; ++k) acc = fmaf(p[k], fws[F_PV + (size_t)k * 64 + c], acc);
            acc = gkbs[i * 64 + c] + acc * inv;
            hb[H_GK + ((((size_t)b * Tc + t) * GEO_Hc + (c >> 4)) * Nc + n) * HDc + (c & 15)] = f2b(acc);
        }
    }
}

// ---- kernel 2: temporal attention (T=12 per node/head) --------------------
__global__ __launch_bounds__(64) void k_tattn(bf16* __restrict__ hb) {
    int blk = blockIdx.x;
    int h = blk & 1;
    int bn = blk >> 1;
    int b = bn >> 9;
    int n = bn & 511;
    size_t base = ((size_t)(b * Nc + n) * T_Hc + h) * (Tc * HDc);

    __shared__ float q[192], kk[192], v[192], s[144];
    int tid = threadIdx.x;
    for (int u = tid; u < 192; u += 64) {
        q[u] = b2f(hb[H_TQ + base + u]);
        kk[u] = b2f(hb[H_TK + base + u]);
        v[u] = b2f(hb[H_TV + base + u]);
    }
    __syncthreads();
    for (int idx = tid; idx < 144; idx += 64) {
        int qi = idx / 12, ki = idx - qi * 12;
        float acc = 0.f;
#pragma unroll
        for (int d = 0; d < 16; ++d) acc = fmaf(q[qi * 16 + d], kk[ki * 16 + d], acc);
        s[idx] = acc * SCALEc;
    }
    __syncthreads();
    if (tid < 12) {
        float mx = -1e30f;
        for (int ki = 0; ki < 12; ++ki) mx = fmaxf(mx, s[tid * 12 + ki]);
        float sum = 0.f;
        for (int ki = 0; ki < 12; ++ki) {
            float p = __expf(s[tid * 12 + ki] - mx);
            s[tid * 12 + ki] = p;
            sum += p;
        }
        float inv = 1.f / sum;
        for (int ki = 0; ki < 12; ++ki) s[tid * 12 + ki] *= inv;
    }
    __syncthreads();
    for (int idx = tid; idx < 192; idx += 64) {
        int qi = idx >> 4, d = idx & 15;
        float acc = 0.f;
#pragma unroll
        for (int ki = 0; ki < 12; ++ki) acc = fmaf(s[qi * 12 + ki], v[ki * 16 + d], acc);
        hb[H_CC + (((size_t)b * Tc + qi) * Nc + n) * Dc + h * HDc + d] = f2b(acc);
    }
}

// ---- kernel 3: spatial attention (geo & sem) ------------------------------
__global__ __launch_bounds__(256) void k_attn(
    bf16* __restrict__ hb, const float* __restrict__ fws,
    size_t QO, size_t KO, size_t VO, int H,
    const void* __restrict__ maskp, const float* __restrict__ dynp, int coff) {
    int blk = blockIdx.x;
    int qchunk = blk & 31;
    int rest = blk >> 5;
    int h = rest % H;
    int rest2 = rest / H;
    int t = rest2 % Tc;
    int b = rest2 / Tc;

    size_t bth = (((size_t)b * Tc + t) * H + h) * (size_t)(Nc * HDc);
    const bf16* Qp = hb + QO + bth;
    const bf16* Kp = hb + KO + bth;
    const bf16* Vp = hb + VO + bth;

    __shared__ float qs[16 * 17];
    __shared__ float P[16 * 513];
    __shared__ float KV[128 * 17];

    int tid = threadIdx.x;
    int q0 = qchunk * 16;
    int mode = (int)fws[F_FLAG];

    {
        int r = tid >> 4, d = tid & 15;
        qs[r * 17 + d] = b2f(Qp[(size_t)(q0 + r) * 16 + d]);
    }

    int ql = tid >> 4;
    int kg = tid & 15;
    int qglob = q0 + ql;

    for (int kt = 0; kt < 4; ++kt) {
        __syncthreads();
        for (int u = tid; u < 2048; u += 256) {
            int r = u >> 4, d = u & 15;
            KV[r * 17 + d] = b2f(Kp[(size_t)(kt * 128 + r) * 16 + d]);
        }
        __syncthreads();
        for (int j = 0; j < 8; ++j) {
            int kl = kg + 16 * j;
            int kk = kt * 128 + kl;
            float acc = 0.f;
#pragma unroll
            for (int d = 0; d < 16; ++d) acc = fmaf(qs[ql * 17 + d], KV[kl * 17 + d], acc);
            acc *= SCALEc;
            if (dynp) acc += dynp[((size_t)b * Nc + qglob) * Nc + kk];
            size_t midx = (size_t)qglob * Nc + kk;
            int mval = (mode == 0) ? (int)((const unsigned char*)maskp)[midx]
                     : (mode == 1) ? ((const int*)maskp)[midx]
                                   : ((const int*)maskp)[2 * midx];   // i64 low word
            P[ql * 513 + kk] = mval ? -1e30f : acc;
        }
    }
    __syncthreads();

    {   // row softmax: 16 threads per row, strided columns
        float mx = -1e30f;
        for (int i2 = 0; i2 < 32; ++i2) mx = fmaxf(mx, P[ql * 513 + kg + 16 * i2]);
        for (int off = 8; off; off >>= 1) mx = fmaxf(mx, __shfl_xor(mx, off, 16));
        float sum = 0.f;
        for (int i2 = 0; i2 < 32; ++i2) {
            float p = __expf(P[ql * 513 + kg + 16 * i2] - mx);
            P[ql * 513 + kg + 16 * i2] = p;
            sum += p;
        }
        for (int off = 8; off; off >>= 1) sum += __shfl_xor(sum, off, 16);
        float inv = 1.f / sum;
        for (int i2 = 0; i2 < 32; ++i2) P[ql * 513 + kg + 16 * i2] *= inv;
    }
    __syncthreads();

    int d = tid & 15;
    int qv = tid >> 4;
    float acc = 0.f;
    for (int kt = 0; kt < 4; ++kt) {
        __syncthreads();
        for (int u = tid; u < 2048; u += 256) {
            int r = u >> 4, dd = u & 15;
            KV[r * 17 + dd] = b2f(Vp[(size_t)(kt * 128 + r) * 16 + dd]);
        }
        __syncthreads();
#pragma unroll 8
        for (int kl = 0; kl < 128; ++kl)
            acc = fmaf(P[qv * 513 + kt * 128 + kl], KV[kl * 17 + d], acc);
    }
    int nq = q0 + qv;
    hb[H_CC + (((size_t)b * Tc + t) * Nc + nq) * Dc + coff + h * HDc + d] = f2b(acc);
}

// ---- kernel 4: output projection ------------------------------------------
__global__ __launch_bounds__(256) void k_out(
    const bf16* __restrict__ hb, const float* __restrict__ proj_w,
    const float* __restrict__ proj_b, float* __restrict__ out) {
    __shared__ float cs[16 * 128];
    int tid = threadIdx.x;
    size_t g0 = (size_t)blockIdx.x * 16;
    for (int u = tid; u < 2048; u += 256) cs[u] = b2f(hb[H_CC + g0 * 128 + u]);
    __syncthreads();
    for (int idx = tid; idx < 2048; idx += 256) {
        int i = idx >> 7, e = idx & 127;
        float v = dotw128f(proj_w + (size_t)e * 128, cs + i * 128) + proj_b[e];
        out[(g0 + i) * 128 + e] = v;
    }
}

extern "C" void kernel_launch(void* const* d_in, const int* in_sizes, int n_in,
                              void* d_out, int out_size, void* d_ws, size_t ws_size,
                              hipStream_t stream) {
    const float* x = (const float*)d_in[0];
    const float* xp = (const float*)d_in[1];
    const float* pattern_keys = (const float*)d_in[2];
    const float* dyn = (const float*)d_in[3];
    const void* geo_mask = d_in[4];
    const void* sem_mask = d_in[5];
    const float* t_qw = (const float*)d_in[6];
    const float* t_kw = (const float*)d_in[7];
    const float* t_vw = (const float*)d_in[8];
    const float* geo_qw = (const float*)d_in[9];
    const float* geo_kw = (const float*)d_in[10];
    const float* geo_vw = (const float*)d_in[11];
    const float* sem_qw = (const float*)d_in[12];
    const float* sem_kw = (const float*)d_in[13];
    const float* sem_vw = (const float*)d_in[14];
    const float* pat_qw = (const float*)d_in[15];
    const float* pat_qb = (const float*)d_in[16];
    const float* pat_kw = (const float*)d_in[17];
    const float* pat_kb = (const float*)d_in[18];
    const float* pat_vw = (const float*)d_in[19];
    const float* pat_vb = (const float*)d_in[20];
    const float* proj_w = (const float*)d_in[21];
    const float* proj_b = (const float*)d_in[22];

    bf16* hb = (bf16*)d_ws;
    float* fws = (float*)d_ws;

    k_prep<<<1, 256, 0, stream>>>(pattern_keys, pat_kw, pat_kb, pat_vw, pat_vb,
                                  (const unsigned char*)geo_mask, fws);
    k_proj<<<(Bc * Tc * Nc) / 16, 256, 0, stream>>>(
        x, xp, t_qw, t_kw, t_vw, geo_qw, geo_kw, geo_vw, sem_qw, sem_kw, sem_vw,
        pat_qw, pat_qb, hb, fws);
    k_tattn<<<Bc * Nc * T_Hc, 64, 0, stream>>>(hb);
    k_attn<<<Bc * Tc * GEO_Hc * 32, 256, 0, stream>>>(
        hb, fws, H_GQ, H_GK, H_GV, GEO_Hc, geo_mask, dyn, 32);
    k_attn<<<Bc * Tc * SEM_Hc * 32, 256, 0, stream>>>(
        hb, fws, H_SQ, H_SK, H_SV, SEM_Hc, sem_mask, nullptr, 96);
    k_out<<<(Bc * Tc * Nc) / 16, 256, 0, stream>>>(hb, proj_w, proj_b, (float*)d_out);
}

// Round 4
// 1103.364 us; speedup vs baseline: 2.1695x; 2.1695x over previous
//
#include <hip/hip_runtime.h>
#include <hip/hip_bf16.h>

using bf16 = __hip_bfloat16;

#define Bc 8
#define Tc 12
#define Nc 512
#define Dc 128
#define T_Hc 2
#define GEO_Hc 4
#define SEM_Hc 2
#define HDc 16
#define SCALEc 0.25f

// ================= ws layout =================
constexpr size_t TSZ = (size_t)Bc * Nc * T_Hc * Tc * HDc;      // 1,572,864
constexpr size_t GSZ = (size_t)Bc * Tc * GEO_Hc * Nc * HDc;    // 3,145,728
constexpr size_t SSZ = (size_t)Bc * Tc * SEM_Hc * Nc * HDc;    // 1,572,864
constexpr size_t CSZ = (size_t)Bc * Tc * Nc * Dc;              // 6,291,456
constexpr size_t H_TQ = 0;
constexpr size_t H_TK = H_TQ + TSZ;
constexpr size_t H_TV = H_TK + TSZ;
constexpr size_t H_GQ = H_TV + TSZ;
constexpr size_t H_GK = H_GQ + GSZ;
constexpr size_t H_GV = H_GK + GSZ;
constexpr size_t H_SQ = H_GV + GSZ;
constexpr size_t H_SK = H_SQ + SSZ;
constexpr size_t H_SV = H_SK + SSZ;
constexpr size_t H_CC = H_SV + SSZ;
constexpr size_t H_END = H_CC + CSZ;                           // 25,165,824 halves
constexpr size_t F_PK = (H_END + 1) / 2;
constexpr size_t F_PV = F_PK + 1024;
constexpr size_t F_FLAG = F_PV + 1024;
// ws need ~50.4 MB (verified fits in R3)

__device__ __forceinline__ float b2f(bf16 v) { return __bfloat162float(v); }
__device__ __forceinline__ bf16 f2b(float v) { return __float2bfloat16(v); }

// ---- kernel: pattern k/v projection (8 blocks, 1 output/thread) -----------
__global__ __launch_bounds__(256) void k_prep(
    const float* __restrict__ pattern_keys, const float* __restrict__ pat_kw,
    const float* __restrict__ pat_kb, const float* __restrict__ pat_vw,
    const float* __restrict__ pat_vb, float* __restrict__ fws) {
    int idx = blockIdx.x * 256 + threadIdx.x;   // 0..2047
    int which = idx >> 10;
    int r = idx & 1023;
    int k = r >> 6, e = r & 63;
    const float4* w = (const float4*)((which ? pat_vw : pat_kw) + (size_t)e * 128);
    const float4* pk = (const float4*)(pattern_keys + (size_t)k * 128);
    float acc = which ? pat_vb[e] : pat_kb[e];
#pragma unroll
    for (int j = 0; j < 32; ++j) {
        float4 a = pk[j], b = w[j];
        acc = fmaf(a.x, b.x, acc); acc = fmaf(a.y, b.y, acc);
        acc = fmaf(a.z, b.z, acc); acc = fmaf(a.w, b.w, acc);
    }
    fws[(which ? F_PV : F_PK) + (size_t)k * 64 + e] = acc;
}

// ---- kernel: mask dtype detection -----------------------------------------
__global__ __launch_bounds__(256) void k_maskdet(
    const unsigned char* __restrict__ mask, float* __restrict__ fws) {
    __shared__ int s_u8, s_odd4;
    int tid = threadIdx.x;
    if (tid == 0) { s_u8 = 0; s_odd4 = 0; }
    __syncthreads();
    int u8 = 0, odd4 = 0;
    for (int i = tid * 16; i < tid * 16 + 16; ++i) {
        unsigned char v = mask[i];
        if (v && (i & 3)) u8 = 1;
        if (v && ((i & 7) == 4)) odd4 = 1;
    }
    if (u8) atomicOr(&s_u8, 1);
    if (odd4) atomicOr(&s_odd4, 1);
    __syncthreads();
    if (tid == 0) fws[F_FLAG] = s_u8 ? 0.f : (s_odd4 ? 1.f : 2.f);
}

// channel -> weight-row pointer for the 384-ch concat GEMM
__device__ __forceinline__ const float* wrow(
    int gc, const float* tq, const float* tk, const float* tv,
    const float* gq, const float* gk, const float* gv,
    const float* sq, const float* sk, const float* sv) {
    if (gc < 32) return tq + (size_t)gc * 128;
    if (gc < 64) return tk + (size_t)(gc - 32) * 128;
    if (gc < 96) return tv + (size_t)(gc - 64) * 128;
    if (gc < 160) return gq + (size_t)(gc - 96) * 128;
    if (gc < 224) return gk + (size_t)(gc - 160) * 128;
    if (gc < 288) return gv + (size_t)(gc - 224) * 128;
    if (gc < 320) return sq + (size_t)(gc - 288) * 128;
    if (gc < 352) return sk + (size_t)(gc - 320) * 128;
    return sv + (size_t)(gc - 352) * 128;
}

// ---- kernel: main projection GEMM X(49152x128) @ Wcat^T(128x384) ----------
__global__ __launch_bounds__(256, 3) void k_projx(
    const float* __restrict__ x,
    const float* __restrict__ t_qw, const float* __restrict__ t_kw,
    const float* __restrict__ t_vw, const float* __restrict__ geo_qw,
    const float* __restrict__ geo_kw, const float* __restrict__ geo_vw,
    const float* __restrict__ sem_qw, const float* __restrict__ sem_kw,
    const float* __restrict__ sem_vw, bf16* __restrict__ hb) {
    __shared__ float xs[64 * 132];   // X tile, full K, padded stride
    __shared__ float wsh[64 * 68];   // W chunk, half K, padded stride

    int tid = threadIdx.x;
    int tok0 = blockIdx.x * 64;
    int ty = tid >> 4, tx = tid & 15;

    // stage X tile once (64 tokens x 128 k)
    for (int u = tid; u < 2048; u += 256) {
        int row = u >> 5, f4 = u & 31;
        *(float4*)&xs[row * 132 + f4 * 4] =
            *(const float4*)(x + (size_t)(tok0 + row) * 128 + f4 * 4);
    }

    for (int chunk = 0; chunk < 6; ++chunk) {
        float acc[4][4] = {};
        for (int kh = 0; kh < 2; ++kh) {
            __syncthreads();   // also covers initial X staging on first iter
            for (int u = tid; u < 1024; u += 256) {
                int row = u >> 4, f4 = u & 15;
                const float* src = wrow(chunk * 64 + row, t_qw, t_kw, t_vw,
                                        geo_qw, geo_kw, geo_vw, sem_qw, sem_kw,
                                        sem_vw) + kh * 64 + f4 * 4;
                *(float4*)&wsh[row * 68 + f4 * 4] = *(const float4*)src;
            }
            __syncthreads();
#pragma unroll 4
            for (int kk = 0; kk < 64; kk += 4) {
                float4 a[4], b[4];
#pragma unroll
                for (int i = 0; i < 4; ++i)
                    a[i] = *(const float4*)&xs[(ty + 16 * i) * 132 + kh * 64 + kk];
#pragma unroll
                for (int j = 0; j < 4; ++j)
                    b[j] = *(const float4*)&wsh[(tx + 16 * j) * 68 + kk];
#pragma unroll
                for (int i = 0; i < 4; ++i)
#pragma unroll
                    for (int j = 0; j < 4; ++j) {
                        acc[i][j] = fmaf(a[i].x, b[j].x, acc[i][j]);
                        acc[i][j] = fmaf(a[i].y, b[j].y, acc[i][j]);
                        acc[i][j] = fmaf(a[i].z, b[j].z, acc[i][j]);
                        acc[i][j] = fmaf(a[i].w, b[j].w, acc[i][j]);
                    }
            }
        }
        // epilogue: scatter 4x4 outputs to bf16 QKV buffers
#pragma unroll
        for (int i = 0; i < 4; ++i) {
            int token = tok0 + ty + 16 * i;
            int b = token / (Tc * Nc);
            int rr = token - b * Tc * Nc;
            int t = rr >> 9;
            int n = rr & 511;
#pragma unroll
            for (int j = 0; j < 4; ++j) {
                int gc = chunk * 64 + tx + 16 * j;
                float v = acc[i][j];
                size_t idx;
                if (gc < 96) {
                    int which = gc >> 5, hh = (gc >> 4) & 1, d = gc & 15;
                    size_t base = which == 0 ? H_TQ : which == 1 ? H_TK : H_TV;
                    idx = base + ((size_t)(b * Nc + n) * T_Hc + hh) * (Tc * HDc)
                          + t * HDc + d;
                } else if (gc < 288) {
                    int r2 = gc - 96;
                    int which = r2 >> 6, h = (r2 >> 4) & 3, d = gc & 15;
                    size_t base = which == 0 ? H_GQ : which == 1 ? H_GK : H_GV;
                    idx = base + (((size_t)b * Tc + t) * GEO_Hc + h) * (Nc * HDc)
                          + n * HDc + d;
                } else {
                    int r2 = gc - 288;
                    int which = r2 >> 5, h = (r2 >> 4) & 1, d = gc & 15;
                    size_t base = which == 0 ? H_SQ : which == 1 ? H_SK : H_SV;
                    idx = base + (((size_t)b * Tc + t) * SEM_Hc + h) * (Nc * HDc)
                          + n * HDc + d;
                }
                hb[idx] = f2b(v);
            }
        }
    }
}

// ---- kernel: pattern-q GEMM + pattern attention fused into geo_k ----------
__global__ __launch_bounds__(256, 2) void k_projp(
    const float* __restrict__ xp, const float* __restrict__ pat_qw,
    const float* __restrict__ pat_qb, const float* __restrict__ fws,
    bf16* __restrict__ hb) {
    __shared__ float xs[64 * 132];
    __shared__ float wsh[64 * 68];
    __shared__ float pks[1024], pvs[1024], pqbs[64];

    int tid = threadIdx.x;
    int tok0 = blockIdx.x * 64;
    int ty = tid >> 4, tx = tid & 15;

    for (int u = tid; u < 2048; u += 256) {
        int row = u >> 5, f4 = u & 31;
        *(float4*)&xs[row * 132 + f4 * 4] =
            *(const float4*)(xp + (size_t)(tok0 + row) * 128 + f4 * 4);
    }
    for (int u = tid; u < 1024; u += 256) {
        pks[u] = fws[F_PK + u];
        pvs[u] = fws[F_PV + u];
    }
    if (tid < 64) pqbs[tid] = pat_qb[tid];

    float acc[4][4] = {};
    for (int kh = 0; kh < 2; ++kh) {
        __syncthreads();
        for (int u = tid; u < 1024; u += 256) {
            int row = u >> 4, f4 = u & 15;
            *(float4*)&wsh[row * 68 + f4 * 4] =
                *(const float4*)(pat_qw + (size_t)row * 128 + kh * 64 + f4 * 4);
        }
        __syncthreads();
#pragma unroll 4
        for (int kk = 0; kk < 64; kk += 4) {
            float4 a[4], b[4];
#pragma unroll
            for (int i = 0; i < 4; ++i)
                a[i] = *(const float4*)&xs[(ty + 16 * i) * 132 + kh * 64 + kk];
#pragma unroll
            for (int j = 0; j < 4; ++j)
                b[j] = *(const float4*)&wsh[(tx + 16 * j) * 68 + kk];
#pragma unroll
            for (int i = 0; i < 4; ++i)
#pragma unroll
                for (int j = 0; j < 4; ++j) {
                    acc[i][j] = fmaf(a[i].x, b[j].x, acc[i][j]);
                    acc[i][j] = fmaf(a[i].y, b[j].y, acc[i][j]);
                    acc[i][j] = fmaf(a[i].z, b[j].z, acc[i][j]);
                    acc[i][j] = fmaf(a[i].w, b[j].w, acc[i][j]);
                }
        }
    }
    __syncthreads();
    // reuse xs as pq tile (stride 68), wsh as logits (stride 17)
    float* pqs = xs;
    float* plogs = wsh;
#pragma unroll
    for (int i = 0; i < 4; ++i)
#pragma unroll
        for (int j = 0; j < 4; ++j)
            pqs[(ty + 16 * i) * 68 + tx + 16 * j] = acc[i][j] + pqbs[tx + 16 * j];
    __syncthreads();
    {   // logits: thread -> (token, 4 pattern slots)
        int tok = tid >> 2, k4 = (tid & 3) * 4;
        for (int k = k4; k < k4 + 4; ++k) {
            float s = 0.f;
#pragma unroll 16
            for (int e = 0; e < 64; ++e)
                s = fmaf(pqs[tok * 68 + e], pks[k * 64 + e], s);
            plogs[tok * 17 + k] = s * SCALEc;
        }
    }
    __syncthreads();
    {   // softmax + geo_k update: thread -> (token, 16 channels)
        int tok = tid >> 2, q = tid & 3;
        float mx = -1e30f;
        for (int k = 0; k < 16; ++k) mx = fmaxf(mx, plogs[tok * 17 + k]);
        float p[16], sum = 0.f;
        for (int k = 0; k < 16; ++k) {
            p[k] = __expf(plogs[tok * 17 + k] - mx);
            sum += p[k];
        }
        float inv = 1.f / sum;
        int token = tok0 + tok;
        int b = token / (Tc * Nc);
        int rr = token - b * Tc * Nc;
        int t = rr >> 9;
        int n = rr & 511;
        for (int cc = 0; cc < 16; ++cc) {
            int c = q * 16 + cc;
            float v = 0.f;
            for (int k = 0; k < 16; ++k) v = fmaf(p[k], pvs[k * 64 + c], v);
            v *= inv;
            size_t idx = H_GK + (((size_t)b * Tc + t) * GEO_Hc + (c >> 4)) * (Nc * HDc)
                         + n * HDc + (c & 15);
            hb[idx] = f2b(b2f(hb[idx]) + v);
        }
    }
}

// ---- kernel: temporal attention (T=12 per node/head) ----------------------
__global__ __launch_bounds__(64) void k_tattn(bf16* __restrict__ hb) {
    int blk = blockIdx.x;
    int h = blk & 1;
    int bn = blk >> 1;
    int b = bn >> 9;
    int n = bn & 511;
    size_t base = ((size_t)(b * Nc + n) * T_Hc + h) * (Tc * HDc);

    __shared__ float q[192], kk[192], v[192], s[144];
    int tid = threadIdx.x;
    for (int u = tid; u < 192; u += 64) {
        q[u] = b2f(hb[H_TQ + base + u]);
        kk[u] = b2f(hb[H_TK + base + u]);
        v[u] = b2f(hb[H_TV + base + u]);
    }
    __syncthreads();
    for (int idx = tid; idx < 144; idx += 64) {
        int qi = idx / 12, ki = idx - qi * 12;
        float acc = 0.f;
#pragma unroll
        for (int d = 0; d < 16; ++d) acc = fmaf(q[qi * 16 + d], kk[ki * 16 + d], acc);
        s[idx] = acc * SCALEc;
    }
    __syncthreads();
    if (tid < 12) {
        float mx = -1e30f;
        for (int ki = 0; ki < 12; ++ki) mx = fmaxf(mx, s[tid * 12 + ki]);
        float sum = 0.f;
        for (int ki = 0; ki < 12; ++ki) {
            float p = __expf(s[tid * 12 + ki] - mx);
            s[tid * 12 + ki] = p;
            sum += p;
        }
        float inv = 1.f / sum;
        for (int ki = 0; ki < 12; ++ki) s[tid * 12 + ki] *= inv;
    }
    __syncthreads();
    for (int idx = tid; idx < 192; idx += 64) {
        int qi = idx >> 4, d = idx & 15;
        float acc = 0.f;
#pragma unroll
        for (int ki = 0; ki < 12; ++ki) acc = fmaf(s[qi * 12 + ki], v[ki * 16 + d], acc);
        hb[H_CC + (((size_t)b * Tc + qi) * Nc + n) * Dc + h * HDc + d] = f2b(acc);
    }
}

// ---- kernel: spatial attention (geo & sem) --------------------------------
__global__ __launch_bounds__(256) void k_attn(
    bf16* __restrict__ hb, const float* __restrict__ fws,
    size_t QO, size_t KO, size_t VO, int H,
    const void* __restrict__ maskp, const float* __restrict__ dynp, int coff) {
    int blk = blockIdx.x;
    int qchunk = blk & 31;
    int rest = blk >> 5;
    int h = rest % H;
    int rest2 = rest / H;
    int t = rest2 % Tc;
    int b = rest2 / Tc;

    size_t bth = (((size_t)b * Tc + t) * H + h) * (size_t)(Nc * HDc);
    const bf16* Qp = hb + QO + bth;
    const bf16* Kp = hb + KO + bth;
    const bf16* Vp = hb + VO + bth;

    __shared__ float qs[16 * 17];
    __shared__ float P[16 * 513];
    __shared__ float KV[128 * 17];

    int tid = threadIdx.x;
    int q0 = qchunk * 16;
    int mode = (int)fws[F_FLAG];

    {
        int r = tid >> 4, d = tid & 15;
        qs[r * 17 + d] = b2f(Qp[(size_t)(q0 + r) * 16 + d]);
    }

    int ql = tid >> 4;
    int kg = tid & 15;
    int qglob = q0 + ql;

    for (int kt = 0; kt < 4; ++kt) {
        __syncthreads();
        for (int u = tid; u < 2048; u += 256) {
            int r = u >> 4, d = u & 15;
            KV[r * 17 + d] = b2f(Kp[(size_t)(kt * 128 + r) * 16 + d]);
        }
        __syncthreads();
        for (int j = 0; j < 8; ++j) {
            int kl = kg + 16 * j;
            int kk = kt * 128 + kl;
            float acc = 0.f;
#pragma unroll
            for (int d = 0; d < 16; ++d) acc = fmaf(qs[ql * 17 + d], KV[kl * 17 + d], acc);
            acc *= SCALEc;
            if (dynp) acc += dynp[((size_t)b * Nc + qglob) * Nc + kk];
            size_t midx = (size_t)qglob * Nc + kk;
            int mval = (mode == 0) ? (int)((const unsigned char*)maskp)[midx]
                     : (mode == 1) ? ((const int*)maskp)[midx]
                                   : ((const int*)maskp)[2 * midx];
            P[ql * 513 + kk] = mval ? -1e30f : acc;
        }
    }
    __syncthreads();

    {
        float mx = -1e30f;
        for (int i2 = 0; i2 < 32; ++i2) mx = fmaxf(mx, P[ql * 513 + kg + 16 * i2]);
        for (int off = 8; off; off >>= 1) mx = fmaxf(mx, __shfl_xor(mx, off, 16));
        float sum = 0.f;
        for (int i2 = 0; i2 < 32; ++i2) {
            float p = __expf(P[ql * 513 + kg + 16 * i2] - mx);
            P[ql * 513 + kg + 16 * i2] = p;
            sum += p;
        }
        for (int off = 8; off; off >>= 1) sum += __shfl_xor(sum, off, 16);
        float inv = 1.f / sum;
        for (int i2 = 0; i2 < 32; ++i2) P[ql * 513 + kg + 16 * i2] *= inv;
    }
    __syncthreads();

    int d = tid & 15;
    int qv = tid >> 4;
    float acc = 0.f;
    for (int kt = 0; kt < 4; ++kt) {
        __syncthreads();
        for (int u = tid; u < 2048; u += 256) {
            int r = u >> 4, dd = u & 15;
            KV[r * 17 + dd] = b2f(Vp[(size_t)(kt * 128 + r) * 16 + dd]);
        }
        __syncthreads();
#pragma unroll 8
        for (int kl = 0; kl < 128; ++kl)
            acc = fmaf(P[qv * 513 + kt * 128 + kl], KV[kl * 17 + d], acc);
    }
    int nq = q0 + qv;
    hb[H_CC + (((size_t)b * Tc + t) * Nc + nq) * Dc + coff + h * HDc + d] = f2b(acc);
}

// ---- kernel: output projection GEMM CC(49152x128) @ proj_w^T --------------
__global__ __launch_bounds__(256, 3) void k_out(
    const bf16* __restrict__ hb, const float* __restrict__ proj_w,
    const float* __restrict__ proj_b, float* __restrict__ out) {
    __shared__ float xs[64 * 132];
    __shared__ float wsh[64 * 68];
    __shared__ float pbs[128];

    int tid = threadIdx.x;
    int tok0 = blockIdx.x * 64;
    int ty = tid >> 4, tx = tid & 15;

    // stage CC tile (bf16 -> fp32): 64 rows x 16 units of 8 halves
    for (int u = tid; u < 1024; u += 256) {
        int row = u >> 4, seg = u & 15;
        uint4 raw = *(const uint4*)(hb + H_CC + (size_t)(tok0 + row) * 128 + seg * 8);
        float f[8];
        unsigned ua[4] = {raw.x, raw.y, raw.z, raw.w};
#pragma unroll
        for (int q = 0; q < 4; ++q) {
            union { unsigned u; float f; } lo, hi;
            lo.u = (ua[q] & 0xFFFFu) << 16;
            hi.u = ua[q] & 0xFFFF0000u;
            f[2 * q] = lo.f;
            f[2 * q + 1] = hi.f;
        }
        int base = row * 132 + seg * 8;
#pragma unroll
        for (int e = 0; e < 8; ++e) xs[base + e] = f[e];
    }
    if (tid < 128) pbs[tid] = proj_b[tid];

    for (int chunk = 0; chunk < 2; ++chunk) {
        float acc[4][4] = {};
        for (int kh = 0; kh < 2; ++kh) {
            __syncthreads();
            for (int u = tid; u < 1024; u += 256) {
                int row = u >> 4, f4 = u & 15;
                *(float4*)&wsh[row * 68 + f4 * 4] =
                    *(const float4*)(proj_w + (size_t)(chunk * 64 + row) * 128
                                     + kh * 64 + f4 * 4);
            }
            __syncthreads();
#pragma unroll 4
            for (int kk = 0; kk < 64; kk += 4) {
                float4 a[4], b[4];
#pragma unroll
                for (int i = 0; i < 4; ++i)
                    a[i] = *(const float4*)&xs[(ty + 16 * i) * 132 + kh * 64 + kk];
#pragma unroll
                for (int j = 0; j < 4; ++j)
                    b[j] = *(const float4*)&wsh[(tx + 16 * j) * 68 + kk];
#pragma unroll
                for (int i = 0; i < 4; ++i)
#pragma unroll
                    for (int j = 0; j < 4; ++j) {
                        acc[i][j] = fmaf(a[i].x, b[j].x, acc[i][j]);
                        acc[i][j] = fmaf(a[i].y, b[j].y, acc[i][j]);
                        acc[i][j] = fmaf(a[i].z, b[j].z, acc[i][j]);
                        acc[i][j] = fmaf(a[i].w, b[j].w, acc[i][j]);
                    }
            }
        }
#pragma unroll
        for (int i = 0; i < 4; ++i) {
            int token = tok0 + ty + 16 * i;
#pragma unroll
            for (int j = 0; j < 4; ++j) {
                int ch = chunk * 64 + tx + 16 * j;
                out[(size_t)token * 128 + ch] = acc[i][j] + pbs[ch];
            }
        }
    }
}

extern "C" void kernel_launch(void* const* d_in, const int* in_sizes, int n_in,
                              void* d_out, int out_size, void* d_ws, size_t ws_size,
                              hipStream_t stream) {
    const float* x = (const float*)d_in[0];
    const float* xp = (const float*)d_in[1];
    const float* pattern_keys = (const float*)d_in[2];
    const float* dyn = (const float*)d_in[3];
    const void* geo_mask = d_in[4];
    const void* sem_mask = d_in[5];
    const float* t_qw = (const float*)d_in[6];
    const float* t_kw = (const float*)d_in[7];
    const float* t_vw = (const float*)d_in[8];
    const float* geo_qw = (const float*)d_in[9];
    const float* geo_kw = (const float*)d_in[10];
    const float* geo_vw = (const float*)d_in[11];
    const float* sem_qw = (const float*)d_in[12];
    const float* sem_kw = (const float*)d_in[13];
    const float* sem_vw = (const float*)d_in[14];
    const float* pat_qw = (const float*)d_in[15];
    const float* pat_qb = (const float*)d_in[16];
    const float* pat_kw = (const float*)d_in[17];
    const float* pat_kb = (const float*)d_in[18];
    const float* pat_vw = (const float*)d_in[19];
    const float* pat_vb = (const float*)d_in[20];
    const float* proj_w = (const float*)d_in[21];
    const float* proj_b = (const float*)d_in[22];

    bf16* hb = (bf16*)d_ws;
    float* fws = (float*)d_ws;

    k_prep<<<8, 256, 0, stream>>>(pattern_keys, pat_kw, pat_kb, pat_vw, pat_vb, fws);
    k_maskdet<<<1, 256, 0, stream>>>((const unsigned char*)geo_mask, fws);
    k_projx<<<768, 256, 0, stream>>>(x, t_qw, t_kw, t_vw, geo_qw, geo_kw, geo_vw,
                                     sem_qw, sem_kw, sem_vw, hb);
    k_projp<<<768, 256, 0, stream>>>(xp, pat_qw, pat_qb, fws, hb);
    k_tattn<<<Bc * Nc * T_Hc, 64, 0, stream>>>(hb);
    k_attn<<<Bc * Tc * GEO_Hc * 32, 256, 0, stream>>>(
        hb, fws, H_GQ, H_GK, H_GV, GEO_Hc, geo_mask, dyn, 32);
    k_attn<<<Bc * Tc * SEM_Hc * 32, 256, 0, stream>>>(
        hb, fws, H_SQ, H_SK, H_SV, SEM_Hc, sem_mask, nullptr, 96);
    k_out<<<768, 256, 0, stream>>>(hb, proj_w, proj_b, (float*)d_out);
}

// Round 5
// 569.751 us; speedup vs baseline: 4.2015x; 1.9366x over previous
//
#include <hip/hip_runtime.h>
#include <hip/hip_bf16.h>

using bf16 = __hip_bfloat16;
typedef __attribute__((ext_vector_type(8))) short short8;
typedef __attribute__((ext_vector_type(4))) float f32x4;

#define Bc 8
#define Tc 12
#define Nc 512
#define Dc 128
#define T_Hc 2
#define GEO_Hc 4
#define SEM_Hc 2
#define HDc 16
#define SCALEc 0.25f

// ================= ws layout =================
constexpr size_t TSZ = (size_t)Bc * Nc * T_Hc * Tc * HDc;      // 1,572,864
constexpr size_t GSZ = (size_t)Bc * Tc * GEO_Hc * Nc * HDc;    // 3,145,728
constexpr size_t SSZ = (size_t)Bc * Tc * SEM_Hc * Nc * HDc;    // 1,572,864
constexpr size_t CSZ = (size_t)Bc * Tc * Nc * Dc;              // 6,291,456
constexpr size_t H_TQ = 0;
constexpr size_t H_TK = H_TQ + TSZ;
constexpr size_t H_TV = H_TK + TSZ;
constexpr size_t H_GQ = H_TV + TSZ;
constexpr size_t H_GK = H_GQ + GSZ;
constexpr size_t H_GV = H_GK + GSZ;
constexpr size_t H_SQ = H_GV + GSZ;
constexpr size_t H_SK = H_SQ + SSZ;
constexpr size_t H_SV = H_SK + SSZ;
constexpr size_t H_CC = H_SV + SSZ;
constexpr size_t H_END = H_CC + CSZ;                           // 25,165,824 halves
constexpr size_t F_PK = (H_END + 1) / 2;
constexpr size_t F_PV = F_PK + 1024;
constexpr size_t F_FLAG = F_PV + 1024;
// ws need ~50.4 MB (fits; verified R3/R4)

__device__ __forceinline__ float b2f(bf16 v) { return __bfloat162float(v); }
__device__ __forceinline__ bf16 f2b(float v) { return __float2bfloat16(v); }
__device__ __forceinline__ short f2bs(float v) {
    bf16 b = __float2bfloat16(v);
    return *reinterpret_cast<short*>(&b);
}

// ---- kernel: pattern k/v projection ---------------------------------------
__global__ __launch_bounds__(256) void k_prep(
    const float* __restrict__ pattern_keys, const float* __restrict__ pat_kw,
    const float* __restrict__ pat_kb, const float* __restrict__ pat_vw,
    const float* __restrict__ pat_vb, float* __restrict__ fws) {
    int idx = blockIdx.x * 256 + threadIdx.x;   // 0..2047
    int which = idx >> 10;
    int r = idx & 1023;
    int k = r >> 6, e = r & 63;
    const float4* w = (const float4*)((which ? pat_vw : pat_kw) + (size_t)e * 128);
    const float4* pk = (const float4*)(pattern_keys + (size_t)k * 128);
    float acc = which ? pat_vb[e] : pat_kb[e];
#pragma unroll
    for (int j = 0; j < 32; ++j) {
        float4 a = pk[j], b = w[j];
        acc = fmaf(a.x, b.x, acc); acc = fmaf(a.y, b.y, acc);
        acc = fmaf(a.z, b.z, acc); acc = fmaf(a.w, b.w, acc);
    }
    fws[(which ? F_PV : F_PK) + (size_t)k * 64 + e] = acc;
}

// ---- kernel: mask dtype detection -----------------------------------------
__global__ __launch_bounds__(256) void k_maskdet(
    const unsigned char* __restrict__ mask, float* __restrict__ fws) {
    __shared__ int s_u8, s_odd4;
    int tid = threadIdx.x;
    if (tid == 0) { s_u8 = 0; s_odd4 = 0; }
    __syncthreads();
    int u8 = 0, odd4 = 0;
    for (int i = tid * 16; i < tid * 16 + 16; ++i) {
        unsigned char v = mask[i];
        if (v && (i & 3)) u8 = 1;
        if (v && ((i & 7) == 4)) odd4 = 1;
    }
    if (u8) atomicOr(&s_u8, 1);
    if (odd4) atomicOr(&s_odd4, 1);
    __syncthreads();
    if (tid == 0) fws[F_FLAG] = s_u8 ? 0.f : (s_odd4 ? 1.f : 2.f);
}

// channel -> weight-row pointer for the 384-ch concat GEMM
__device__ __forceinline__ const float* wrow(
    int gc, const float* tq, const float* tk, const float* tv,
    const float* gq, const float* gk, const float* gv,
    const float* sq, const float* sk, const float* sv) {
    if (gc < 32) return tq + (size_t)gc * 128;
    if (gc < 64) return tk + (size_t)(gc - 32) * 128;
    if (gc < 96) return tv + (size_t)(gc - 64) * 128;
    if (gc < 160) return gq + (size_t)(gc - 96) * 128;
    if (gc < 224) return gk + (size_t)(gc - 160) * 128;
    if (gc < 288) return gv + (size_t)(gc - 224) * 128;
    if (gc < 320) return sq + (size_t)(gc - 288) * 128;
    if (gc < 352) return sk + (size_t)(gc - 320) * 128;
    return sv + (size_t)(gc - 352) * 128;
}

// ---- kernel: main projection GEMM X(49152x128) @ Wcat^T(128x384) ----------
__global__ __launch_bounds__(256, 3) void k_projx(
    const float* __restrict__ x,
    const float* __restrict__ t_qw, const float* __restrict__ t_kw,
    const float* __restrict__ t_vw, const float* __restrict__ geo_qw,
    const float* __restrict__ geo_kw, const float* __restrict__ geo_vw,
    const float* __restrict__ sem_qw, const float* __restrict__ sem_kw,
    const float* __restrict__ sem_vw, bf16* __restrict__ hb) {
    __shared__ float xs[64 * 132];
    __shared__ float wsh[64 * 68];

    int tid = threadIdx.x;
    int tok0 = blockIdx.x * 64;
    int ty = tid >> 4, tx = tid & 15;

    for (int u = tid; u < 2048; u += 256) {
        int row = u >> 5, f4 = u & 31;
        *(float4*)&xs[row * 132 + f4 * 4] =
            *(const float4*)(x + (size_t)(tok0 + row) * 128 + f4 * 4);
    }

    for (int chunk = 0; chunk < 6; ++chunk) {
        float acc[4][4] = {};
        for (int kh = 0; kh < 2; ++kh) {
            __syncthreads();
            for (int u = tid; u < 1024; u += 256) {
                int row = u >> 4, f4 = u & 15;
                const float* src = wrow(chunk * 64 + row, t_qw, t_kw, t_vw,
                                        geo_qw, geo_kw, geo_vw, sem_qw, sem_kw,
                                        sem_vw) + kh * 64 + f4 * 4;
                *(float4*)&wsh[row * 68 + f4 * 4] = *(const float4*)src;
            }
            __syncthreads();
#pragma unroll 4
            for (int kk = 0; kk < 64; kk += 4) {
                float4 a[4], b[4];
#pragma unroll
                for (int i = 0; i < 4; ++i)
                    a[i] = *(const float4*)&xs[(ty + 16 * i) * 132 + kh * 64 + kk];
#pragma unroll
                for (int j = 0; j < 4; ++j)
                    b[j] = *(const float4*)&wsh[(tx + 16 * j) * 68 + kk];
#pragma unroll
                for (int i = 0; i < 4; ++i)
#pragma unroll
                    for (int j = 0; j < 4; ++j) {
                        acc[i][j] = fmaf(a[i].x, b[j].x, acc[i][j]);
                        acc[i][j] = fmaf(a[i].y, b[j].y, acc[i][j]);
                        acc[i][j] = fmaf(a[i].z, b[j].z, acc[i][j]);
                        acc[i][j] = fmaf(a[i].w, b[j].w, acc[i][j]);
                    }
            }
        }
#pragma unroll
        for (int i = 0; i < 4; ++i) {
            int token = tok0 + ty + 16 * i;
            int b = token / (Tc * Nc);
            int rr = token - b * Tc * Nc;
            int t = rr >> 9;
            int n = rr & 511;
#pragma unroll
            for (int j = 0; j < 4; ++j) {
                int gc = chunk * 64 + tx + 16 * j;
                float v = acc[i][j];
                size_t idx;
                if (gc < 96) {
                    int which = gc >> 5, hh = (gc >> 4) & 1, d = gc & 15;
                    size_t base = which == 0 ? H_TQ : which == 1 ? H_TK : H_TV;
                    idx = base + ((size_t)(b * Nc + n) * T_Hc + hh) * (Tc * HDc)
                          + t * HDc + d;
                } else if (gc < 288) {
                    int r2 = gc - 96;
                    int which = r2 >> 6, h = (r2 >> 4) & 3, d = gc & 15;
                    size_t base = which == 0 ? H_GQ : which == 1 ? H_GK : H_GV;
                    idx = base + (((size_t)b * Tc + t) * GEO_Hc + h) * (Nc * HDc)
                          + n * HDc + d;
                } else {
                    int r2 = gc - 288;
                    int which = r2 >> 5, h = (r2 >> 4) & 1, d = gc & 15;
                    size_t base = which == 0 ? H_SQ : which == 1 ? H_SK : H_SV;
                    idx = base + (((size_t)b * Tc + t) * SEM_Hc + h) * (Nc * HDc)
                          + n * HDc + d;
                }
                hb[idx] = f2b(v);
            }
        }
    }
}

// ---- kernel: pattern-q GEMM + pattern attention fused into geo_k ----------
__global__ __launch_bounds__(256, 2) void k_projp(
    const float* __restrict__ xp, const float* __restrict__ pat_qw,
    const float* __restrict__ pat_qb, const float* __restrict__ fws,
    bf16* __restrict__ hb) {
    __shared__ float xs[64 * 132];
    __shared__ float wsh[64 * 68];
    __shared__ float pks[1024], pvs[1024], pqbs[64];

    int tid = threadIdx.x;
    int tok0 = blockIdx.x * 64;
    int ty = tid >> 4, tx = tid & 15;

    for (int u = tid; u < 2048; u += 256) {
        int row = u >> 5, f4 = u & 31;
        *(float4*)&xs[row * 132 + f4 * 4] =
            *(const float4*)(xp + (size_t)(tok0 + row) * 128 + f4 * 4);
    }
    for (int u = tid; u < 1024; u += 256) {
        pks[u] = fws[F_PK + u];
        pvs[u] = fws[F_PV + u];
    }
    if (tid < 64) pqbs[tid] = pat_qb[tid];

    float acc[4][4] = {};
    for (int kh = 0; kh < 2; ++kh) {
        __syncthreads();
        for (int u = tid; u < 1024; u += 256) {
            int row = u >> 4, f4 = u & 15;
            *(float4*)&wsh[row * 68 + f4 * 4] =
                *(const float4*)(pat_qw + (size_t)row * 128 + kh * 64 + f4 * 4);
        }
        __syncthreads();
#pragma unroll 4
        for (int kk = 0; kk < 64; kk += 4) {
            float4 a[4], b[4];
#pragma unroll
            for (int i = 0; i < 4; ++i)
                a[i] = *(const float4*)&xs[(ty + 16 * i) * 132 + kh * 64 + kk];
#pragma unroll
            for (int j = 0; j < 4; ++j)
                b[j] = *(const float4*)&wsh[(tx + 16 * j) * 68 + kk];
#pragma unroll
            for (int i = 0; i < 4; ++i)
#pragma unroll
                for (int j = 0; j < 4; ++j) {
                    acc[i][j] = fmaf(a[i].x, b[j].x, acc[i][j]);
                    acc[i][j] = fmaf(a[i].y, b[j].y, acc[i][j]);
                    acc[i][j] = fmaf(a[i].z, b[j].z, acc[i][j]);
                    acc[i][j] = fmaf(a[i].w, b[j].w, acc[i][j]);
                }
        }
    }
    __syncthreads();
    float* pqs = xs;    // reuse
    float* plogs = wsh; // reuse
#pragma unroll
    for (int i = 0; i < 4; ++i)
#pragma unroll
        for (int j = 0; j < 4; ++j)
            pqs[(ty + 16 * i) * 68 + tx + 16 * j] = acc[i][j] + pqbs[tx + 16 * j];
    __syncthreads();
    {
        int tok = tid >> 2, k4 = (tid & 3) * 4;
        for (int k = k4; k < k4 + 4; ++k) {
            float s = 0.f;
#pragma unroll 16
            for (int e = 0; e < 64; ++e)
                s = fmaf(pqs[tok * 68 + e], pks[k * 64 + e], s);
            plogs[tok * 17 + k] = s * SCALEc;
        }
    }
    __syncthreads();
    {
        int tok = tid >> 2, q = tid & 3;
        float mx = -1e30f;
        for (int k = 0; k < 16; ++k) mx = fmaxf(mx, plogs[tok * 17 + k]);
        float p[16], sum = 0.f;
        for (int k = 0; k < 16; ++k) {
            p[k] = __expf(plogs[tok * 17 + k] - mx);
            sum += p[k];
        }
        float inv = 1.f / sum;
        int token = tok0 + tok;
        int b = token / (Tc * Nc);
        int rr = token - b * Tc * Nc;
        int t = rr >> 9;
        int n = rr & 511;
        for (int cc = 0; cc < 16; ++cc) {
            int c = q * 16 + cc;
            float v = 0.f;
            for (int k = 0; k < 16; ++k) v = fmaf(p[k], pvs[k * 64 + c], v);
            v *= inv;
            size_t idx = H_GK + (((size_t)b * Tc + t) * GEO_Hc + (c >> 4)) * (Nc * HDc)
                         + n * HDc + (c & 15);
            hb[idx] = f2b(b2f(hb[idx]) + v);
        }
    }
}

// ---- kernel: temporal attention (T=12 per node/head) ----------------------
__global__ __launch_bounds__(64) void k_tattn(bf16* __restrict__ hb) {
    int blk = blockIdx.x;
    int h = blk & 1;
    int bn = blk >> 1;
    int b = bn >> 9;
    int n = bn & 511;
    size_t base = ((size_t)(b * Nc + n) * T_Hc + h) * (Tc * HDc);

    __shared__ float q[192], kk[192], v[192], s[144];
    int tid = threadIdx.x;
    for (int u = tid; u < 192; u += 64) {
        q[u] = b2f(hb[H_TQ + base + u]);
        kk[u] = b2f(hb[H_TK + base + u]);
        v[u] = b2f(hb[H_TV + base + u]);
    }
    __syncthreads();
    for (int idx = tid; idx < 144; idx += 64) {
        int qi = idx / 12, ki = idx - qi * 12;
        float acc = 0.f;
#pragma unroll
        for (int d = 0; d < 16; ++d) acc = fmaf(q[qi * 16 + d], kk[ki * 16 + d], acc);
        s[idx] = acc * SCALEc;
    }
    __syncthreads();
    if (tid < 12) {
        float mx = -1e30f;
        for (int ki = 0; ki < 12; ++ki) mx = fmaxf(mx, s[tid * 12 + ki]);
        float sum = 0.f;
        for (int ki = 0; ki < 12; ++ki) {
            float p = __expf(s[tid * 12 + ki] - mx);
            s[tid * 12 + ki] = p;
            sum += p;
        }
        float inv = 1.f / sum;
        for (int ki = 0; ki < 12; ++ki) s[tid * 12 + ki] *= inv;
    }
    __syncthreads();
    for (int idx = tid; idx < 192; idx += 64) {
        int qi = idx >> 4, d = idx & 15;
        float acc = 0.f;
#pragma unroll
        for (int ki = 0; ki < 12; ++ki) acc = fmaf(s[qi * 12 + ki], v[ki * 16 + d], acc);
        hb[H_CC + (((size_t)b * Tc + qi) * Nc + n) * Dc + h * HDc + d] = f2b(acc);
    }
}

// ---- kernel: MFMA spatial attention (geo & sem), flash-style --------------
// grid: B*T*H*4 blocks; block = 4 waves; wave handles 2 q-tiles of 16.
__global__ __launch_bounds__(256, 4) void k_attn2(
    bf16* __restrict__ hb, const float* __restrict__ fws,
    size_t QO, size_t KO, size_t VO, int H,
    const void* __restrict__ maskp, const float* __restrict__ dynp, int coff) {
    __shared__ short vt[16 * 552];        // V^T, row d, padded stride
    __shared__ short pbuf[4][16 * 168];   // per-wave P (q-major, padded)

    int bid = blockIdx.x;
    int part = bid & 3;
    int bth_lin = bid >> 2;
    int h = bth_lin % H;
    int rest = bth_lin / H;
    int t = rest % Tc;
    int b = rest / Tc;

    size_t bth = (((size_t)b * Tc + t) * H + h) * (size_t)(Nc * HDc);
    const bf16* Qp = hb + QO + bth;
    const bf16* Kp = hb + KO + bth;
    const bf16* Vp = hb + VO + bth;

    int tid = threadIdx.x;
    int w = tid >> 6;
    int lane = tid & 63;
    int l15 = lane & 15;
    int quad = lane >> 4;

    // stage V^T (coalesced global read, scattered LDS write)
    for (int idx = tid; idx < 8192; idx += 256) {
        int k = idx >> 4, d = idx & 15;
        vt[d * 552 + k] = *reinterpret_cast<const short*>(Vp + idx);
    }
    __syncthreads();

    int mode = (int)fws[F_FLAG];
    const unsigned char* m8 = (const unsigned char*)maskp;
    const int* m32 = (const int*)maskp;
    short* pw = &pbuf[w][0];

    for (int qq = 0; qq < 2; ++qq) {
        int q0 = part * 128 + (w * 2 + qq) * 16;
        short8 aq = {0, 0, 0, 0, 0, 0, 0, 0};
        if (quad < 2)
            aq = *(const short8*)(Qp + (size_t)(q0 + l15) * 16 + quad * 8);

        float m_i[4], l_i[4];
        f32x4 O = {0.f, 0.f, 0.f, 0.f};
#pragma unroll
        for (int i = 0; i < 4; ++i) { m_i[i] = -3e38f; l_i[i] = 0.f; }

        for (int ch = 0; ch < 4; ++ch) {
            float S[8][4];
            // ---- S = Q K^T (zero-padded K=32 MFMA), direct-global frags ----
#pragma unroll
            for (int kt = 0; kt < 8; ++kt) {
                int kabs = ch * 128 + kt * 16;
                short8 bk = {0, 0, 0, 0, 0, 0, 0, 0};
                if (quad < 2)
                    bk = *(const short8*)(Kp + (size_t)(kabs + l15) * 16 + quad * 8);
                f32x4 z = {0.f, 0.f, 0.f, 0.f};
                f32x4 r = __builtin_amdgcn_mfma_f32_16x16x32_bf16(aq, bk, z, 0, 0, 0);
#pragma unroll
                for (int i = 0; i < 4; ++i) S[kt][i] = r[i];
            }
            // ---- scale + bias + mask (C-layout coalesced reads) ----
#pragma unroll
            for (int kt = 0; kt < 8; ++kt) {
                int k = ch * 128 + kt * 16 + l15;
#pragma unroll
                for (int i = 0; i < 4; ++i) {
                    int q = q0 + quad * 4 + i;
                    size_t midx = (size_t)q * Nc + k;
                    float s = S[kt][i] * SCALEc;
                    if (dynp) s += dynp[((size_t)b * Nc + q) * Nc + k];
                    int mv = (mode == 0) ? (int)m8[midx]
                           : (mode == 1) ? m32[midx]
                                         : m32[2 * midx];
                    S[kt][i] = mv ? -1e30f : s;
                }
            }
            // ---- online softmax over the 128-k chunk ----
#pragma unroll
            for (int i = 0; i < 4; ++i) {
                float cm = S[0][i];
#pragma unroll
                for (int kt = 1; kt < 8; ++kt) cm = fmaxf(cm, S[kt][i]);
                cm = fmaxf(cm, __shfl_xor(cm, 1));
                cm = fmaxf(cm, __shfl_xor(cm, 2));
                cm = fmaxf(cm, __shfl_xor(cm, 4));
                cm = fmaxf(cm, __shfl_xor(cm, 8));
                float mnew = fmaxf(m_i[i], cm);
                float alpha = __expf(m_i[i] - mnew);
                m_i[i] = mnew;
                l_i[i] *= alpha;
                O[i] *= alpha;
                float psum = 0.f;
#pragma unroll
                for (int kt = 0; kt < 8; ++kt) {
                    float p = __expf(S[kt][i] - mnew);
                    S[kt][i] = p;
                    psum += p;
                }
                psum += __shfl_xor(psum, 1);
                psum += __shfl_xor(psum, 2);
                psum += __shfl_xor(psum, 4);
                psum += __shfl_xor(psum, 8);
                l_i[i] += psum;
            }
            // ---- P chunk -> LDS (bf16, q-major) ----
#pragma unroll
            for (int kt = 0; kt < 8; ++kt)
#pragma unroll
                for (int i = 0; i < 4; ++i)
                    pw[(quad * 4 + i) * 168 + kt * 16 + l15] = f2bs(S[kt][i]);
            // ---- O += P V  (A-frag from P, B-frag from V^T) ----
#pragma unroll
            for (int kw = 0; kw < 4; ++kw) {
                short8 ap = *(const short8*)(pw + l15 * 168 + kw * 32 + quad * 8);
                short8 bv = *(const short8*)(vt + l15 * 552 + ch * 128 + kw * 32 + quad * 8);
                O = __builtin_amdgcn_mfma_f32_16x16x32_bf16(ap, bv, O, 0, 0, 0);
            }
        }
        // ---- epilogue: O / l -> H_CC ----
#pragma unroll
        for (int i = 0; i < 4; ++i) {
            int q = q0 + quad * 4 + i;
            float v = O[i] / l_i[i];
            hb[H_CC + (((size_t)b * Tc + t) * Nc + q) * Dc + coff + h * HDc + l15] =
                f2b(v);
        }
    }
}

// ---- kernel: output projection GEMM CC(49152x128) @ proj_w^T --------------
__global__ __launch_bounds__(256, 3) void k_out(
    const bf16* __restrict__ hb, const float* __restrict__ proj_w,
    const float* __restrict__ proj_b, float* __restrict__ out) {
    __shared__ float xs[64 * 132];
    __shared__ float wsh[64 * 68];
    __shared__ float pbs[128];

    int tid = threadIdx.x;
    int tok0 = blockIdx.x * 64;
    int ty = tid >> 4, tx = tid & 15;

    for (int u = tid; u < 1024; u += 256) {
        int row = u >> 4, seg = u & 15;
        uint4 raw = *(const uint4*)(hb + H_CC + (size_t)(tok0 + row) * 128 + seg * 8);
        float f[8];
        unsigned ua[4] = {raw.x, raw.y, raw.z, raw.w};
#pragma unroll
        for (int q = 0; q < 4; ++q) {
            union { unsigned u; float f; } lo, hi;
            lo.u = (ua[q] & 0xFFFFu) << 16;
            hi.u = ua[q] & 0xFFFF0000u;
            f[2 * q] = lo.f;
            f[2 * q + 1] = hi.f;
        }
        int base = row * 132 + seg * 8;
#pragma unroll
        for (int e = 0; e < 8; ++e) xs[base + e] = f[e];
    }
    if (tid < 128) pbs[tid] = proj_b[tid];

    for (int chunk = 0; chunk < 2; ++chunk) {
        float acc[4][4] = {};
        for (int kh = 0; kh < 2; ++kh) {
            __syncthreads();
            for (int u = tid; u < 1024; u += 256) {
                int row = u >> 4, f4 = u & 15;
                *(float4*)&wsh[row * 68 + f4 * 4] =
                    *(const float4*)(proj_w + (size_t)(chunk * 64 + row) * 128
                                     + kh * 64 + f4 * 4);
            }
            __syncthreads();
#pragma unroll 4
            for (int kk = 0; kk < 64; kk += 4) {
                float4 a[4], b[4];
#pragma unroll
                for (int i = 0; i < 4; ++i)
                    a[i] = *(const float4*)&xs[(ty + 16 * i) * 132 + kh * 64 + kk];
#pragma unroll
                for (int j = 0; j < 4; ++j)
                    b[j] = *(const float4*)&wsh[(tx + 16 * j) * 68 + kk];
#pragma unroll
                for (int i = 0; i < 4; ++i)
#pragma unroll
                    for (int j = 0; j < 4; ++j) {
                        acc[i][j] = fmaf(a[i].x, b[j].x, acc[i][j]);
                        acc[i][j] = fmaf(a[i].y, b[j].y, acc[i][j]);
                        acc[i][j] = fmaf(a[i].z, b[j].z, acc[i][j]);
                        acc[i][j] = fmaf(a[i].w, b[j].w, acc[i][j]);
                    }
            }
        }
#pragma unroll
        for (int i = 0; i < 4; ++i) {
            int token = tok0 + ty + 16 * i;
#pragma unroll
            for (int j = 0; j < 4; ++j) {
                int ch = chunk * 64 + tx + 16 * j;
                out[(size_t)token * 128 + ch] = acc[i][j] + pbs[ch];
            }
        }
    }
}

extern "C" void kernel_launch(void* const* d_in, const int* in_sizes, int n_in,
                              void* d_out, int out_size, void* d_ws, size_t ws_size,
                              hipStream_t stream) {
    const float* x = (const float*)d_in[0];
    const float* xp = (const float*)d_in[1];
    const float* pattern_keys = (const float*)d_in[2];
    const float* dyn = (const float*)d_in[3];
    const void* geo_mask = d_in[4];
    const void* sem_mask = d_in[5];
    const float* t_qw = (const float*)d_in[6];
    const float* t_kw = (const float*)d_in[7];
    const float* t_vw = (const float*)d_in[8];
    const float* geo_qw = (const float*)d_in[9];
    const float* geo_kw = (const float*)d_in[10];
    const float* geo_vw = (const float*)d_in[11];
    const float* sem_qw = (const float*)d_in[12];
    const float* sem_kw = (const float*)d_in[13];
    const float* sem_vw = (const float*)d_in[14];
    const float* pat_qw = (const float*)d_in[15];
    const float* pat_qb = (const float*)d_in[16];
    const float* pat_kw = (const float*)d_in[17];
    const float* pat_kb = (const float*)d_in[18];
    const float* pat_vw = (const float*)d_in[19];
    const float* pat_vb = (const float*)d_in[20];
    const float* proj_w = (const float*)d_in[21];
    const float* proj_b = (const float*)d_in[22];

    bf16* hb = (bf16*)d_ws;
    float* fws = (float*)d_ws;

    k_prep<<<8, 256, 0, stream>>>(pattern_keys, pat_kw, pat_kb, pat_vw, pat_vb, fws);
    k_maskdet<<<1, 256, 0, stream>>>((const unsigned char*)geo_mask, fws);
    k_projx<<<768, 256, 0, stream>>>(x, t_qw, t_kw, t_vw, geo_qw, geo_kw, geo_vw,
                                     sem_qw, sem_kw, sem_vw, hb);
    k_projp<<<768, 256, 0, stream>>>(xp, pat_qw, pat_qb, fws, hb);
    k_tattn<<<Bc * Nc * T_Hc, 64, 0, stream>>>(hb);
    k_attn2<<<Bc * Tc * GEO_Hc * 4, 256, 0, stream>>>(
        hb, fws, H_GQ, H_GK, H_GV, GEO_Hc, geo_mask, dyn, 32);
    k_attn2<<<Bc * Tc * SEM_Hc * 4, 256, 0, stream>>>(
        hb, fws, H_SQ, H_SK, H_SV, SEM_Hc, sem_mask, nullptr, 96);
    k_out<<<768, 256, 0, stream>>>(hb, proj_w, proj_b, (float*)d_out);
}

// Round 6
// 412.885 us; speedup vs baseline: 5.7977x; 1.3799x over previous
//
#include <hip/hip_runtime.h>
#include <hip/hip_bf16.h>

using bf16 = __hip_bfloat16;
typedef __attribute__((ext_vector_type(8))) short short8;
typedef __attribute__((ext_vector_type(4))) float f32x4;

#define Bc 8
#define Tc 12
#define Nc 512
#define Dc 128
#define T_Hc 2
#define GEO_Hc 4
#define SEM_Hc 2
#define HDc 16
#define SCALEc 0.25f

// ================= ws layout =================
constexpr size_t TSZ = (size_t)Bc * Nc * T_Hc * Tc * HDc;      // 1,572,864
constexpr size_t GSZ = (size_t)Bc * Tc * GEO_Hc * Nc * HDc;    // 3,145,728
constexpr size_t SSZ = (size_t)Bc * Tc * SEM_Hc * Nc * HDc;    // 1,572,864
constexpr size_t CSZ = (size_t)Bc * Tc * Nc * Dc;              // 6,291,456
constexpr size_t H_TQ = 0;
constexpr size_t H_TK = H_TQ + TSZ;
constexpr size_t H_TV = H_TK + TSZ;
constexpr size_t H_GQ = H_TV + TSZ;
constexpr size_t H_GK = H_GQ + GSZ;
constexpr size_t H_GV = H_GK + GSZ;
constexpr size_t H_SQ = H_GV + GSZ;
constexpr size_t H_SK = H_SQ + SSZ;
constexpr size_t H_SV = H_SK + SSZ;
constexpr size_t H_CC = H_SV + SSZ;
constexpr size_t H_END = H_CC + CSZ;                           // 25,165,824 halves
constexpr size_t F_PK = (H_END + 1) / 2;
constexpr size_t F_PV = F_PK + 1024;
constexpr size_t F_FLAG = F_PV + 1024;
// masked-bias buffers overlay the dead T-QKV region (k_tattn runs first):
constexpr size_t H_BG = H_TQ;                  // geo: 8*512*512 = 2,097,152 halves
constexpr size_t H_BS = H_TQ + 2097152;        // sem: 512*512   =   262,144 halves
// ws need ~50.4 MB (fits; verified R3-R5)

__device__ __forceinline__ float b2f(bf16 v) { return __bfloat162float(v); }
__device__ __forceinline__ bf16 f2b(float v) { return __float2bfloat16(v); }
__device__ __forceinline__ short f2bs(float v) {
    bf16 b = __float2bfloat16(v);
    return *reinterpret_cast<short*>(&b);
}
__device__ __forceinline__ float bs2f(short s) {
    union { unsigned u; float f; } x;
    x.u = ((unsigned)(unsigned short)s) << 16;
    return x.f;
}

// ---- kernel: pattern k/v projection ---------------------------------------
__global__ __launch_bounds__(256) void k_prep(
    const float* __restrict__ pattern_keys, const float* __restrict__ pat_kw,
    const float* __restrict__ pat_kb, const float* __restrict__ pat_vw,
    const float* __restrict__ pat_vb, float* __restrict__ fws) {
    int idx = blockIdx.x * 256 + threadIdx.x;   // 0..2047
    int which = idx >> 10;
    int r = idx & 1023;
    int k = r >> 6, e = r & 63;
    const float4* w = (const float4*)((which ? pat_vw : pat_kw) + (size_t)e * 128);
    const float4* pk = (const float4*)(pattern_keys + (size_t)k * 128);
    float acc = which ? pat_vb[e] : pat_kb[e];
#pragma unroll
    for (int j = 0; j < 32; ++j) {
        float4 a = pk[j], b = w[j];
        acc = fmaf(a.x, b.x, acc); acc = fmaf(a.y, b.y, acc);
        acc = fmaf(a.z, b.z, acc); acc = fmaf(a.w, b.w, acc);
    }
    fws[(which ? F_PV : F_PK) + (size_t)k * 64 + e] = acc;
}

// ---- kernel: mask dtype detection -----------------------------------------
__global__ __launch_bounds__(256) void k_maskdet(
    const unsigned char* __restrict__ mask, float* __restrict__ fws) {
    __shared__ int s_u8, s_odd4;
    int tid = threadIdx.x;
    if (tid == 0) { s_u8 = 0; s_odd4 = 0; }
    __syncthreads();
    int u8 = 0, odd4 = 0;
    for (int i = tid * 16; i < tid * 16 + 16; ++i) {
        unsigned char v = mask[i];
        if (v && (i & 3)) u8 = 1;
        if (v && ((i & 7) == 4)) odd4 = 1;
    }
    if (u8) atomicOr(&s_u8, 1);
    if (odd4) atomicOr(&s_odd4, 1);
    __syncthreads();
    if (tid == 0) fws[F_FLAG] = s_u8 ? 0.f : (s_odd4 ? 1.f : 2.f);
}

// ---- kernel: build masked-bias buffers (bf16) -----------------------------
__global__ __launch_bounds__(256) void k_bias(
    const float* __restrict__ dyn, const unsigned char* __restrict__ gm,
    const unsigned char* __restrict__ sm, const float* __restrict__ fws,
    bf16* __restrict__ hb) {
    size_t gid = (size_t)blockIdx.x * 256 + threadIdx.x;
    int mode = (int)fws[F_FLAG];
    if (gid < 2097152) {
        size_t rem = gid & 262143;   // q*512+k
        int mv = (mode == 0) ? (int)gm[rem]
               : (mode == 1) ? ((const int*)gm)[rem]
                             : ((const int*)gm)[2 * rem];
        hb[H_BG + gid] = f2b(mv ? -1e30f : dyn[gid]);
    } else if (gid < 2097152 + 262144) {
        size_t sid = gid - 2097152;
        int mv = (mode == 0) ? (int)sm[sid]
               : (mode == 1) ? ((const int*)sm)[sid]
                             : ((const int*)sm)[2 * sid];
        hb[H_BS + sid] = f2b(mv ? -1e30f : 0.f);
    }
}

// channel -> weight-row pointer for the 384-ch concat GEMM
__device__ __forceinline__ const float* wrow(
    int gc, const float* tq, const float* tk, const float* tv,
    const float* gq, const float* gk, const float* gv,
    const float* sq, const float* sk, const float* sv) {
    if (gc < 32) return tq + (size_t)gc * 128;
    if (gc < 64) return tk + (size_t)(gc - 32) * 128;
    if (gc < 96) return tv + (size_t)(gc - 64) * 128;
    if (gc < 160) return gq + (size_t)(gc - 96) * 128;
    if (gc < 224) return gk + (size_t)(gc - 160) * 128;
    if (gc < 288) return gv + (size_t)(gc - 224) * 128;
    if (gc < 320) return sq + (size_t)(gc - 288) * 128;
    if (gc < 352) return sk + (size_t)(gc - 320) * 128;
    return sv + (size_t)(gc - 352) * 128;
}

// ---- kernel: main projection GEMM X(49152x128) @ Wcat^T(128x384) ----------
// geo-q and sem-q channels are pre-scaled by SCALE (folded into attention).
__global__ __launch_bounds__(256, 3) void k_projx(
    const float* __restrict__ x,
    const float* __restrict__ t_qw, const float* __restrict__ t_kw,
    const float* __restrict__ t_vw, const float* __restrict__ geo_qw,
    const float* __restrict__ geo_kw, const float* __restrict__ geo_vw,
    const float* __restrict__ sem_qw, const float* __restrict__ sem_kw,
    const float* __restrict__ sem_vw, bf16* __restrict__ hb) {
    __shared__ float xs[64 * 132];
    __shared__ float wsh[64 * 68];

    int tid = threadIdx.x;
    int tok0 = blockIdx.x * 64;
    int ty = tid >> 4, tx = tid & 15;

    for (int u = tid; u < 2048; u += 256) {
        int row = u >> 5, f4 = u & 31;
        *(float4*)&xs[row * 132 + f4 * 4] =
            *(const float4*)(x + (size_t)(tok0 + row) * 128 + f4 * 4);
    }

    for (int chunk = 0; chunk < 6; ++chunk) {
        float acc[4][4] = {};
        for (int kh = 0; kh < 2; ++kh) {
            __syncthreads();
            for (int u = tid; u < 1024; u += 256) {
                int row = u >> 4, f4 = u & 15;
                const float* src = wrow(chunk * 64 + row, t_qw, t_kw, t_vw,
                                        geo_qw, geo_kw, geo_vw, sem_qw, sem_kw,
                                        sem_vw) + kh * 64 + f4 * 4;
                *(float4*)&wsh[row * 68 + f4 * 4] = *(const float4*)src;
            }
            __syncthreads();
#pragma unroll 4
            for (int kk = 0; kk < 64; kk += 4) {
                float4 a[4], b[4];
#pragma unroll
                for (int i = 0; i < 4; ++i)
                    a[i] = *(const float4*)&xs[(ty + 16 * i) * 132 + kh * 64 + kk];
#pragma unroll
                for (int j = 0; j < 4; ++j)
                    b[j] = *(const float4*)&wsh[(tx + 16 * j) * 68 + kk];
#pragma unroll
                for (int i = 0; i < 4; ++i)
#pragma unroll
                    for (int j = 0; j < 4; ++j) {
                        acc[i][j] = fmaf(a[i].x, b[j].x, acc[i][j]);
                        acc[i][j] = fmaf(a[i].y, b[j].y, acc[i][j]);
                        acc[i][j] = fmaf(a[i].z, b[j].z, acc[i][j]);
                        acc[i][j] = fmaf(a[i].w, b[j].w, acc[i][j]);
                    }
            }
        }
#pragma unroll
        for (int i = 0; i < 4; ++i) {
            int token = tok0 + ty + 16 * i;
            int b = token / (Tc * Nc);
            int rr = token - b * Tc * Nc;
            int t = rr >> 9;
            int n = rr & 511;
#pragma unroll
            for (int j = 0; j < 4; ++j) {
                int gc = chunk * 64 + tx + 16 * j;
                float v = acc[i][j];
                size_t idx;
                if (gc < 96) {
                    int which = gc >> 5, hh = (gc >> 4) & 1, d = gc & 15;
                    size_t base = which == 0 ? H_TQ : which == 1 ? H_TK : H_TV;
                    idx = base + ((size_t)(b * Nc + n) * T_Hc + hh) * (Tc * HDc)
                          + t * HDc + d;
                } else if (gc < 288) {
                    int r2 = gc - 96;
                    int which = r2 >> 6, h = (r2 >> 4) & 3, d = gc & 15;
                    if (which == 0) v *= SCALEc;       // pre-scale geo q
                    size_t base = which == 0 ? H_GQ : which == 1 ? H_GK : H_GV;
                    idx = base + (((size_t)b * Tc + t) * GEO_Hc + h) * (Nc * HDc)
                          + n * HDc + d;
                } else {
                    int r2 = gc - 288;
                    int which = r2 >> 5, h = (r2 >> 4) & 1, d = gc & 15;
                    if (which == 0) v *= SCALEc;       // pre-scale sem q
                    size_t base = which == 0 ? H_SQ : which == 1 ? H_SK : H_SV;
                    idx = base + (((size_t)b * Tc + t) * SEM_Hc + h) * (Nc * HDc)
                          + n * HDc + d;
                }
                hb[idx] = f2b(v);
            }
        }
    }
}

// ---- kernel: pattern-q GEMM + pattern attention fused into geo_k ----------
__global__ __launch_bounds__(256, 2) void k_projp(
    const float* __restrict__ xp, const float* __restrict__ pat_qw,
    const float* __restrict__ pat_qb, const float* __restrict__ fws,
    bf16* __restrict__ hb) {
    __shared__ float xs[64 * 132];
    __shared__ float wsh[64 * 68];
    __shared__ float pks[1024], pvs[1024], pqbs[64];

    int tid = threadIdx.x;
    int tok0 = blockIdx.x * 64;
    int ty = tid >> 4, tx = tid & 15;

    for (int u = tid; u < 2048; u += 256) {
        int row = u >> 5, f4 = u & 31;
        *(float4*)&xs[row * 132 + f4 * 4] =
            *(const float4*)(xp + (size_t)(tok0 + row) * 128 + f4 * 4);
    }
    for (int u = tid; u < 1024; u += 256) {
        pks[u] = fws[F_PK + u];
        pvs[u] = fws[F_PV + u];
    }
    if (tid < 64) pqbs[tid] = pat_qb[tid];

    float acc[4][4] = {};
    for (int kh = 0; kh < 2; ++kh) {
        __syncthreads();
        for (int u = tid; u < 1024; u += 256) {
            int row = u >> 4, f4 = u & 15;
            *(float4*)&wsh[row * 68 + f4 * 4] =
                *(const float4*)(pat_qw + (size_t)row * 128 + kh * 64 + f4 * 4);
        }
        __syncthreads();
#pragma unroll 4
        for (int kk = 0; kk < 64; kk += 4) {
            float4 a[4], b[4];
#pragma unroll
            for (int i = 0; i < 4; ++i)
                a[i] = *(const float4*)&xs[(ty + 16 * i) * 132 + kh * 64 + kk];
#pragma unroll
            for (int j = 0; j < 4; ++j)
                b[j] = *(const float4*)&wsh[(tx + 16 * j) * 68 + kk];
#pragma unroll
            for (int i = 0; i < 4; ++i)
#pragma unroll
                for (int j = 0; j < 4; ++j) {
                    acc[i][j] = fmaf(a[i].x, b[j].x, acc[i][j]);
                    acc[i][j] = fmaf(a[i].y, b[j].y, acc[i][j]);
                    acc[i][j] = fmaf(a[i].z, b[j].z, acc[i][j]);
                    acc[i][j] = fmaf(a[i].w, b[j].w, acc[i][j]);
                }
        }
    }
    __syncthreads();
    float* pqs = xs;    // reuse
    float* plogs = wsh; // reuse
#pragma unroll
    for (int i = 0; i < 4; ++i)
#pragma unroll
        for (int j = 0; j < 4; ++j)
            pqs[(ty + 16 * i) * 68 + tx + 16 * j] = acc[i][j] + pqbs[tx + 16 * j];
    __syncthreads();
    {
        int tok = tid >> 2, k4 = (tid & 3) * 4;
        for (int k = k4; k < k4 + 4; ++k) {
            float s = 0.f;
#pragma unroll 16
            for (int e = 0; e < 64; ++e)
                s = fmaf(pqs[tok * 68 + e], pks[k * 64 + e], s);
            plogs[tok * 17 + k] = s * SCALEc;
        }
    }
    __syncthreads();
    {
        int tok = tid >> 2, q = tid & 3;
        float mx = -1e30f;
        for (int k = 0; k < 16; ++k) mx = fmaxf(mx, plogs[tok * 17 + k]);
        float p[16], sum = 0.f;
        for (int k = 0; k < 16; ++k) {
            p[k] = __expf(plogs[tok * 17 + k] - mx);
            sum += p[k];
        }
        float inv = 1.f / sum;
        int token = tok0 + tok;
        int b = token / (Tc * Nc);
        int rr = token - b * Tc * Nc;
        int t = rr >> 9;
        int n = rr & 511;
        for (int cc = 0; cc < 16; ++cc) {
            int c = q * 16 + cc;
            float v = 0.f;
            for (int k = 0; k < 16; ++k) v = fmaf(p[k], pvs[k * 64 + c], v);
            v *= inv;
            size_t idx = H_GK + (((size_t)b * Tc + t) * GEO_Hc + (c >> 4)) * (Nc * HDc)
                         + n * HDc + (c & 15);
            hb[idx] = f2b(b2f(hb[idx]) + v);
        }
    }
}

// ---- kernel: temporal attention (T=12 per node/head) ----------------------
__global__ __launch_bounds__(64) void k_tattn(bf16* __restrict__ hb) {
    int blk = blockIdx.x;
    int h = blk & 1;
    int bn = blk >> 1;
    int b = bn >> 9;
    int n = bn & 511;
    size_t base = ((size_t)(b * Nc + n) * T_Hc + h) * (Tc * HDc);

    __shared__ float q[192], kk[192], v[192], s[144];
    int tid = threadIdx.x;
    for (int u = tid; u < 192; u += 64) {
        q[u] = b2f(hb[H_TQ + base + u]);
        kk[u] = b2f(hb[H_TK + base + u]);
        v[u] = b2f(hb[H_TV + base + u]);
    }
    __syncthreads();
    for (int idx = tid; idx < 144; idx += 64) {
        int qi = idx / 12, ki = idx - qi * 12;
        float acc = 0.f;
#pragma unroll
        for (int d = 0; d < 16; ++d) acc = fmaf(q[qi * 16 + d], kk[ki * 16 + d], acc);
        s[idx] = acc * SCALEc;
    }
    __syncthreads();
    if (tid < 12) {
        float mx = -1e30f;
        for (int ki = 0; ki < 12; ++ki) mx = fmaxf(mx, s[tid * 12 + ki]);
        float sum = 0.f;
        for (int ki = 0; ki < 12; ++ki) {
            float p = __expf(s[tid * 12 + ki] - mx);
            s[tid * 12 + ki] = p;
            sum += p;
        }
        float inv = 1.f / sum;
        for (int ki = 0; ki < 12; ++ki) s[tid * 12 + ki] *= inv;
    }
    __syncthreads();
    for (int idx = tid; idx < 192; idx += 64) {
        int qi = idx >> 4, d = idx & 15;
        float acc = 0.f;
#pragma unroll
        for (int ki = 0; ki < 12; ++ki) acc = fmaf(s[qi * 12 + ki], v[ki * 16 + d], acc);
        hb[H_CC + (((size_t)b * Tc + qi) * Nc + n) * Dc + h * HDc + d] = f2b(acc);
    }
}

// ---- kernel: MFMA spatial attention (geo & sem), S^T formulation ----------
// S^T = K·Q^T + bias (bias = masked dyn / -1e30, MFMA C-operand; Q pre-scaled).
// Lane owns q = lane&15; k = quad*4+reg. V^T and P XOR-swizzled in LDS.
__global__ __launch_bounds__(256, 4) void k_attn2(
    bf16* __restrict__ hb, size_t QO, size_t KO, size_t VO, int H,
    const bf16* __restrict__ biasp, size_t bstride, int coff) {
    __shared__ short vt[16 * 512];       // V^T, row d, swizzled granules
    __shared__ short pbuf[4][16 * 128];  // per-wave P chunk, row q, swizzled
    __shared__ float lt[4][16];
    __shared__ float at[4][16];

    int bid = blockIdx.x;
    int part = bid & 3;
    int bth_lin = bid >> 2;
    int h = bth_lin % H;
    int rest = bth_lin / H;
    int t = rest % Tc;
    int b = rest / Tc;

    size_t bth = (((size_t)b * Tc + t) * H + h) * (size_t)(Nc * HDc);
    const bf16* Qp = hb + QO + bth;
    const bf16* Kp = hb + KO + bth;
    const bf16* Vp = hb + VO + bth;
    const bf16* bp = biasp + (size_t)b * bstride;

    int tid = threadIdx.x;
    int w = tid >> 6;
    int lane = tid & 63;
    int l15 = lane & 15;
    int quad = lane >> 4;

    // stage V^T: vt[d][swz(k)] ; swizzle 16B granules by d&7
    for (int idx = tid; idx < 8192; idx += 256) {
        int k = idx >> 4, d = idx & 15;
        int kk = ((((k >> 3) & 7) ^ (d & 7)) << 3) | (k & ~63) | (k & 7);
        vt[d * 512 + kk] = *reinterpret_cast<const short*>(Vp + idx);
    }
    __syncthreads();

    short* pw = &pbuf[w][0];
    float* lw = lt[w];
    float* aw = at[w];
    int sw = l15 & 7;

    for (int qq = 0; qq < 2; ++qq) {
        int q0 = part * 128 + w * 32 + qq * 16;
        int qg = q0 + l15;
        short8 bq = {0, 0, 0, 0, 0, 0, 0, 0};
        if (quad < 2) bq = *(const short8*)(Qp + (size_t)qg * 16 + quad * 8);

        float m_i = -3e38f, l_i = 0.f;
        f32x4 O = {0.f, 0.f, 0.f, 0.f};

        for (int ch = 0; ch < 4; ++ch) {
            int kabs0 = ch * 128;
            f32x4 S[8];
            // ---- S^T tiles: mfma(K, Q, C=bias) ----
#pragma unroll
            for (int kt = 0; kt < 8; ++kt) {
                int kabs = kabs0 + kt * 16;
                short4 bb = *(const short4*)(bp + (size_t)qg * 512 + kabs + quad * 4);
                f32x4 c;
                c[0] = bs2f(bb.x); c[1] = bs2f(bb.y);
                c[2] = bs2f(bb.z); c[3] = bs2f(bb.w);
                short8 ak = {0, 0, 0, 0, 0, 0, 0, 0};
                if (quad < 2)
                    ak = *(const short8*)(Kp + (size_t)(kabs + l15) * 16 + quad * 8);
                S[kt] = __builtin_amdgcn_mfma_f32_16x16x32_bf16(ak, bq, c, 0, 0, 0);
            }
            // ---- online softmax (lane = q domain) ----
            float cm = S[0][0];
#pragma unroll
            for (int kt = 0; kt < 8; ++kt)
#pragma unroll
                for (int r = 0; r < 4; ++r) cm = fmaxf(cm, S[kt][r]);
            cm = fmaxf(cm, __shfl_xor(cm, 16));
            cm = fmaxf(cm, __shfl_xor(cm, 32));
            float mnew = fmaxf(m_i, cm);
            float alpha = __expf(m_i - mnew);
            m_i = mnew;
            float psum = 0.f;
#pragma unroll
            for (int kt = 0; kt < 8; ++kt) {
#pragma unroll
                for (int r = 0; r < 4; ++r) {
                    float p = __expf(S[kt][r] - mnew);
                    S[kt][r] = p;
                    psum += p;
                }
            }
            psum += __shfl_xor(psum, 16);
            psum += __shfl_xor(psum, 32);
            l_i = l_i * alpha + psum;
            if (quad == 0) aw[l15] = alpha;
            // ---- P chunk -> LDS (b64 packed, swizzled) ----
#pragma unroll
            for (int kt = 0; kt < 8; ++kt) {
                short4 pk4;
                pk4.x = f2bs(S[kt][0]); pk4.y = f2bs(S[kt][1]);
                pk4.z = f2bs(S[kt][2]); pk4.w = f2bs(S[kt][3]);
                int g = 2 * kt + (quad >> 1);
                *(short4*)&pw[l15 * 128 + ((g ^ sw) << 3) + ((quad & 1) << 2)] = pk4;
            }
            // ---- O rescale (O domain: q = quad*4+r) then O += P V ----
            float4 a4 = *(float4*)&aw[quad * 4];
            O[0] *= a4.x; O[1] *= a4.y; O[2] *= a4.z; O[3] *= a4.w;
#pragma unroll
            for (int kw = 0; kw < 4; ++kw) {
                int g = 4 * kw + quad;
                short8 ap = *(const short8*)&pw[l15 * 128 + ((g ^ sw) << 3)];
                short8 bv = *(const short8*)&vt[l15 * 512 + kabs0 + ((g ^ sw) << 3)];
                O = __builtin_amdgcn_mfma_f32_16x16x32_bf16(ap, bv, O, 0, 0, 0);
            }
        }
        // ---- epilogue: O / l -> H_CC (lane: d = l15, q = quad*4+r) ----
        if (quad == 0) lw[l15] = l_i;
        float4 l4 = *(float4*)&lw[quad * 4];
        float inv0 = 1.f / l4.x, inv1 = 1.f / l4.y, inv2 = 1.f / l4.z, inv3 = 1.f / l4.w;
        size_t obase = H_CC + (((size_t)b * Tc + t) * Nc + q0) * Dc + coff + h * HDc + l15;
        hb[obase + (size_t)(quad * 4 + 0) * Dc] = f2b(O[0] * inv0);
        hb[obase + (size_t)(quad * 4 + 1) * Dc] = f2b(O[1] * inv1);
        hb[obase + (size_t)(quad * 4 + 2) * Dc] = f2b(O[2] * inv2);
        hb[obase + (size_t)(quad * 4 + 3) * Dc] = f2b(O[3] * inv3);
    }
}

// ---- kernel: output projection GEMM CC(49152x128) @ proj_w^T --------------
__global__ __launch_bounds__(256, 3) void k_out(
    const bf16* __restrict__ hb, const float* __restrict__ proj_w,
    const float* __restrict__ proj_b, float* __restrict__ out) {
    __shared__ float xs[64 * 132];
    __shared__ float wsh[64 * 68];
    __shared__ float pbs[128];

    int tid = threadIdx.x;
    int tok0 = blockIdx.x * 64;
    int ty = tid >> 4, tx = tid & 15;

    for (int u = tid; u < 1024; u += 256) {
        int row = u >> 4, seg = u & 15;
        uint4 raw = *(const uint4*)(hb + H_CC + (size_t)(tok0 + row) * 128 + seg * 8);
        float f[8];
        unsigned ua[4] = {raw.x, raw.y, raw.z, raw.w};
#pragma unroll
        for (int q = 0; q < 4; ++q) {
            union { unsigned u; float f; } lo, hi;
            lo.u = (ua[q] & 0xFFFFu) << 16;
            hi.u = ua[q] & 0xFFFF0000u;
            f[2 * q] = lo.f;
            f[2 * q + 1] = hi.f;
        }
        int base = row * 132 + seg * 8;
#pragma unroll
        for (int e = 0; e < 8; ++e) xs[base + e] = f[e];
    }
    if (tid < 128) pbs[tid] = proj_b[tid];

    for (int chunk = 0; chunk < 2; ++chunk) {
        float acc[4][4] = {};
        for (int kh = 0; kh < 2; ++kh) {
            __syncthreads();
            for (int u = tid; u < 1024; u += 256) {
                int row = u >> 4, f4 = u & 15;
                *(float4*)&wsh[row * 68 + f4 * 4] =
                    *(const float4*)(proj_w + (size_t)(chunk * 64 + row) * 128
                                     + kh * 64 + f4 * 4);
            }
            __syncthreads();
#pragma unroll 4
            for (int kk = 0; kk < 64; kk += 4) {
                float4 a[4], b[4];
#pragma unroll
                for (int i = 0; i < 4; ++i)
                    a[i] = *(const float4*)&xs[(ty + 16 * i) * 132 + kh * 64 + kk];
#pragma unroll
                for (int j = 0; j < 4; ++j)
                    b[j] = *(const float4*)&wsh[(tx + 16 * j) * 68 + kk];
#pragma unroll
                for (int i = 0; i < 4; ++i)
#pragma unroll
                    for (int j = 0; j < 4; ++j) {
                        acc[i][j] = fmaf(a[i].x, b[j].x, acc[i][j]);
                        acc[i][j] = fmaf(a[i].y, b[j].y, acc[i][j]);
                        acc[i][j] = fmaf(a[i].z, b[j].z, acc[i][j]);
                        acc[i][j] = fmaf(a[i].w, b[j].w, acc[i][j]);
                    }
            }
        }
#pragma unroll
        for (int i = 0; i < 4; ++i) {
            int token = tok0 + ty + 16 * i;
#pragma unroll
            for (int j = 0; j < 4; ++j) {
                int ch = chunk * 64 + tx + 16 * j;
                out[(size_t)token * 128 + ch] = acc[i][j] + pbs[ch];
            }
        }
    }
}

extern "C" void kernel_launch(void* const* d_in, const int* in_sizes, int n_in,
                              void* d_out, int out_size, void* d_ws, size_t ws_size,
                              hipStream_t stream) {
    const float* x = (const float*)d_in[0];
    const float* xp = (const float*)d_in[1];
    const float* pattern_keys = (const float*)d_in[2];
    const float* dyn = (const float*)d_in[3];
    const void* geo_mask = d_in[4];
    const void* sem_mask = d_in[5];
    const float* t_qw = (const float*)d_in[6];
    const float* t_kw = (const float*)d_in[7];
    const float* t_vw = (const float*)d_in[8];
    const float* geo_qw = (const float*)d_in[9];
    const float* geo_kw = (const float*)d_in[10];
    const float* geo_vw = (const float*)d_in[11];
    const float* sem_qw = (const float*)d_in[12];
    const float* sem_kw = (const float*)d_in[13];
    const float* sem_vw = (const float*)d_in[14];
    const float* pat_qw = (const float*)d_in[15];
    const float* pat_qb = (const float*)d_in[16];
    const float* pat_kw = (const float*)d_in[17];
    const float* pat_kb = (const float*)d_in[18];
    const float* pat_vw = (const float*)d_in[19];
    const float* pat_vb = (const float*)d_in[20];
    const float* proj_w = (const float*)d_in[21];
    const float* proj_b = (const float*)d_in[22];

    bf16* hb = (bf16*)d_ws;
    float* fws = (float*)d_ws;

    k_prep<<<8, 256, 0, stream>>>(pattern_keys, pat_kw, pat_kb, pat_vw, pat_vb, fws);
    k_maskdet<<<1, 256, 0, stream>>>((const unsigned char*)geo_mask, fws);
    k_projx<<<768, 256, 0, stream>>>(x, t_qw, t_kw, t_vw, geo_qw, geo_kw, geo_vw,
                                     sem_qw, sem_kw, sem_vw, hb);
    k_projp<<<768, 256, 0, stream>>>(xp, pat_qw, pat_qb, fws, hb);
    k_tattn<<<Bc * Nc * T_Hc, 64, 0, stream>>>(hb);
    // bias build overwrites the (now dead) temporal QKV region
    k_bias<<<9216, 256, 0, stream>>>(dyn, (const unsigned char*)geo_mask,
                                     (const unsigned char*)sem_mask, fws, hb);
    k_attn2<<<Bc * Tc * GEO_Hc * 4, 256, 0, stream>>>(
        hb, H_GQ, H_GK, H_GV, GEO_Hc, hb + H_BG, (size_t)Nc * Nc, 32);
    k_attn2<<<Bc * Tc * SEM_Hc * 4, 256, 0, stream>>>(
        hb, H_SQ, H_SK, H_SV, SEM_Hc, hb + H_BS, 0, 96);
    k_out<<<768, 256, 0, stream>>>(hb, proj_w, proj_b, (float*)d_out);
}

// Round 7
// 364.733 us; speedup vs baseline: 6.5631x; 1.1320x over previous
//
#include <hip/hip_runtime.h>
#include <hip/hip_bf16.h>

using bf16 = __hip_bfloat16;
typedef __attribute__((ext_vector_type(8))) short short8;
typedef __attribute__((ext_vector_type(4))) float f32x4;

#define Bc 8
#define Tc 12
#define Nc 512
#define Dc 128
#define T_Hc 2
#define GEO_Hc 4
#define SEM_Hc 2
#define HDc 16
#define SCALEc 0.25f

// ================= ws layout =================
constexpr size_t TSZ = (size_t)Bc * Nc * T_Hc * Tc * HDc;      // 1,572,864
constexpr size_t GSZ = (size_t)Bc * Tc * GEO_Hc * Nc * HDc;    // 3,145,728
constexpr size_t SSZ = (size_t)Bc * Tc * SEM_Hc * Nc * HDc;    // 1,572,864
constexpr size_t CSZ = (size_t)Bc * Tc * Nc * Dc;              // 6,291,456
constexpr size_t H_TQ = 0;
constexpr size_t H_TK = H_TQ + TSZ;
constexpr size_t H_TV = H_TK + TSZ;
constexpr size_t H_GQ = H_TV + TSZ;
constexpr size_t H_GK = H_GQ + GSZ;
constexpr size_t H_GV = H_GK + GSZ;
constexpr size_t H_SQ = H_GV + GSZ;
constexpr size_t H_SK = H_SQ + SSZ;
constexpr size_t H_SV = H_SK + SSZ;
constexpr size_t H_CC = H_SV + SSZ;
constexpr size_t H_END = H_CC + CSZ;                           // 25,165,824 halves
constexpr size_t F_PK = (H_END + 1) / 2;
constexpr size_t F_PV = F_PK + 1024;
constexpr size_t F_FLAG = F_PV + 1024;
// bf16 weight copies for the MFMA GEMMs (≈ +0.23 MB):
constexpr size_t H_W2X = 2 * (F_FLAG + 64);    // [384][256] K2-duplicated
constexpr size_t H_W2O = H_W2X + 384 * 256;    // [128][128]
// masked-bias buffers overlay the dead T-QKV region (k_tattn runs first):
constexpr size_t H_BG = H_TQ;                  // geo: 8*512*512 halves
constexpr size_t H_BS = H_TQ + 2097152;        // sem: 512*512 halves
// ws need ~50.6 MB

__device__ __forceinline__ float b2f(bf16 v) { return __bfloat162float(v); }
__device__ __forceinline__ bf16 f2b(float v) { return __float2bfloat16(v); }
__device__ __forceinline__ short f2bs(float v) {
    bf16 b = __float2bfloat16(v);
    return *reinterpret_cast<short*>(&b);
}
__device__ __forceinline__ float bs2f(short s) {
    union { unsigned u; float f; } x;
    x.u = ((unsigned)(unsigned short)s) << 16;
    return x.f;
}

// ---- kernel: pattern k/v projection ---------------------------------------
__global__ __launch_bounds__(256) void k_prep(
    const float* __restrict__ pattern_keys, const float* __restrict__ pat_kw,
    const float* __restrict__ pat_kb, const float* __restrict__ pat_vw,
    const float* __restrict__ pat_vb, float* __restrict__ fws) {
    int idx = blockIdx.x * 256 + threadIdx.x;   // 0..2047
    int which = idx >> 10;
    int r = idx & 1023;
    int k = r >> 6, e = r & 63;
    const float4* w = (const float4*)((which ? pat_vw : pat_kw) + (size_t)e * 128);
    const float4* pk = (const float4*)(pattern_keys + (size_t)k * 128);
    float acc = which ? pat_vb[e] : pat_kb[e];
#pragma unroll
    for (int j = 0; j < 32; ++j) {
        float4 a = pk[j], b = w[j];
        acc = fmaf(a.x, b.x, acc); acc = fmaf(a.y, b.y, acc);
        acc = fmaf(a.z, b.z, acc); acc = fmaf(a.w, b.w, acc);
    }
    fws[(which ? F_PV : F_PK) + (size_t)k * 64 + e] = acc;
}

// ---- kernel: mask dtype detection -----------------------------------------
__global__ __launch_bounds__(256) void k_maskdet(
    const unsigned char* __restrict__ mask, float* __restrict__ fws) {
    __shared__ int s_u8, s_odd4;
    int tid = threadIdx.x;
    if (tid == 0) { s_u8 = 0; s_odd4 = 0; }
    __syncthreads();
    int u8 = 0, odd4 = 0;
    for (int i = tid * 16; i < tid * 16 + 16; ++i) {
        unsigned char v = mask[i];
        if (v && (i & 3)) u8 = 1;
        if (v && ((i & 7) == 4)) odd4 = 1;
    }
    if (u8) atomicOr(&s_u8, 1);
    if (odd4) atomicOr(&s_odd4, 1);
    __syncthreads();
    if (tid == 0) fws[F_FLAG] = s_u8 ? 0.f : (s_odd4 ? 1.f : 2.f);
}

// channel -> weight-row pointer for the 384-ch concat GEMM
__device__ __forceinline__ const float* wrow(
    int gc, const float* tq, const float* tk, const float* tv,
    const float* gq, const float* gk, const float* gv,
    const float* sq, const float* sk, const float* sv) {
    if (gc < 32) return tq + (size_t)gc * 128;
    if (gc < 64) return tk + (size_t)(gc - 32) * 128;
    if (gc < 96) return tv + (size_t)(gc - 64) * 128;
    if (gc < 160) return gq + (size_t)(gc - 96) * 128;
    if (gc < 224) return gk + (size_t)(gc - 160) * 128;
    if (gc < 288) return gv + (size_t)(gc - 224) * 128;
    if (gc < 320) return sq + (size_t)(gc - 288) * 128;
    if (gc < 352) return sk + (size_t)(gc - 320) * 128;
    return sv + (size_t)(gc - 352) * 128;
}

// ---- kernel: bf16 weight conversion for MFMA GEMMs ------------------------
// W2X: 384 rows x 256 (each fp32 w duplicated at 2k,2k+1 to match hi/lo X);
// geo-q and sem-q rows pre-scaled by SCALE. W2O: proj_w as plain bf16.
__global__ __launch_bounds__(256) void k_wcvt(
    const float* __restrict__ t_qw, const float* __restrict__ t_kw,
    const float* __restrict__ t_vw, const float* __restrict__ geo_qw,
    const float* __restrict__ geo_kw, const float* __restrict__ geo_vw,
    const float* __restrict__ sem_qw, const float* __restrict__ sem_kw,
    const float* __restrict__ sem_vw, const float* __restrict__ proj_w,
    bf16* __restrict__ hb) {
    int gid = blockIdx.x * 256 + threadIdx.x;   // 0..65535
    if (gid < 49152) {
        int row = gid >> 7, k = gid & 127;
        const float* src = wrow(row, t_qw, t_kw, t_vw, geo_qw, geo_kw, geo_vw,
                                sem_qw, sem_kw, sem_vw);
        float v = src[k];
        if ((row >= 96 && row < 160) || (row >= 288 && row < 320)) v *= SCALEc;
        bf16 bv = f2b(v);
        hb[H_W2X + (size_t)row * 256 + 2 * k] = bv;
        hb[H_W2X + (size_t)row * 256 + 2 * k + 1] = bv;
    } else {
        int g = gid - 49152;
        hb[H_W2O + g] = f2b(proj_w[g]);
    }
}

// ---- kernel: build masked-bias buffers (bf16) -----------------------------
__global__ __launch_bounds__(256) void k_bias(
    const float* __restrict__ dyn, const unsigned char* __restrict__ gm,
    const unsigned char* __restrict__ sm, const float* __restrict__ fws,
    bf16* __restrict__ hb) {
    size_t gid = (size_t)blockIdx.x * 256 + threadIdx.x;
    int mode = (int)fws[F_FLAG];
    if (gid < 2097152) {
        size_t rem = gid & 262143;   // q*512+k
        int mv = (mode == 0) ? (int)gm[rem]
               : (mode == 1) ? ((const int*)gm)[rem]
                             : ((const int*)gm)[2 * rem];
        hb[H_BG + gid] = f2b(mv ? -1e30f : dyn[gid]);
    } else if (gid < 2097152 + 262144) {
        size_t sid = gid - 2097152;
        int mv = (mode == 0) ? (int)sm[sid]
               : (mode == 1) ? ((const int*)sm)[sid]
                             : ((const int*)sm)[2 * sid];
        hb[H_BS + sid] = f2b(mv ? -1e30f : 0.f);
    }
}

// ---- kernel: MFMA projection GEMM X(49152x128) @ Wcat^T(128x384) ----------
// X split hi/lo bf16 (K2=256); per block: M-tile 128, all 6 N-chunks.
// LDS 64 KB, XOR-swizzled 16B granules. B-frags direct from global (L2-hot).
__global__ __launch_bounds__(256, 2) void k_projx(
    const float* __restrict__ x, bf16* __restrict__ hb) {
    __shared__ short xs[128 * 256];   // 65536 B

    int tid = threadIdx.x;
    int m0 = blockIdx.x * 128;
    int b = m0 / (Tc * Nc);
    int rr = m0 - b * Tc * Nc;
    int t = rr >> 9;
    int n0 = rr & 511;

    // stage + convert X tile: fp32 -> interleaved hi/lo bf16
    for (int u = tid; u < 4096; u += 256) {
        int row = u >> 5, g = u & 31;
        float4 v = *(const float4*)(x + (size_t)(m0 + row) * 128 + g * 4);
        short8 s;
        short h0 = f2bs(v.x); s[0] = h0; s[1] = f2bs(v.x - bs2f(h0));
        short h1 = f2bs(v.y); s[2] = h1; s[3] = f2bs(v.y - bs2f(h1));
        short h2 = f2bs(v.z); s[4] = h2; s[5] = f2bs(v.z - bs2f(h2));
        short h3 = f2bs(v.w); s[6] = h3; s[7] = f2bs(v.w - bs2f(h3));
        *(short8*)&xs[row * 256 + ((g ^ (row & 7)) << 3)] = s;
    }
    __syncthreads();

    int w = tid >> 6;
    int lane = tid & 63;
    int l15 = lane & 15;
    int quad = lane >> 4;
    const bf16* w2 = hb + H_W2X;

    for (int nc = 0; nc < 6; ++nc) {
        f32x4 acc[2][4];
#pragma unroll
        for (int i = 0; i < 2; ++i)
#pragma unroll
            for (int j = 0; j < 4; ++j) acc[i][j] = (f32x4){0.f, 0.f, 0.f, 0.f};

#pragma unroll
        for (int ks = 0; ks < 8; ++ks) {
            int r0 = w * 32 + l15;
            int r1 = r0 + 16;
            short8 a0 = *(const short8*)&xs[r0 * 256 + (((ks * 4 + quad) ^ (r0 & 7)) << 3)];
            short8 a1 = *(const short8*)&xs[r1 * 256 + (((ks * 4 + quad) ^ (r1 & 7)) << 3)];
#pragma unroll
            for (int nj = 0; nj < 4; ++nj) {
                short8 bfr = *(const short8*)(w2 + (size_t)(nc * 64 + nj * 16 + l15) * 256
                                              + ks * 32 + quad * 8);
                acc[0][nj] = __builtin_amdgcn_mfma_f32_16x16x32_bf16(a0, bfr, acc[0][nj], 0, 0, 0);
                acc[1][nj] = __builtin_amdgcn_mfma_f32_16x16x32_bf16(a1, bfr, acc[1][nj], 0, 0, 0);
            }
        }
        // epilogue scatter (D: row=token via quad*4+r, col=channel via l15)
#pragma unroll
        for (int nj = 0; nj < 4; ++nj) {
            int gc = nc * 64 + nj * 16 + l15;
            int tile16 = nc * 4 + nj;
            int d = gc & 15;
#pragma unroll
            for (int i = 0; i < 2; ++i) {
                int nrow0 = n0 + w * 32 + i * 16 + quad * 4;
#pragma unroll
                for (int r = 0; r < 4; ++r) {
                    int n = nrow0 + r;
                    float v = acc[i][nj][r];
                    size_t idx;
                    if (tile16 < 6) {
                        int which = gc >> 5, hh = (gc >> 4) & 1;
                        size_t base = which == 0 ? H_TQ : which == 1 ? H_TK : H_TV;
                        idx = base + ((size_t)(b * Nc + n) * T_Hc + hh) * (Tc * HDc)
                              + t * HDc + d;
                    } else if (tile16 < 18) {
                        int r2 = gc - 96;
                        int which = r2 >> 6, h = (r2 >> 4) & 3;
                        size_t base = which == 0 ? H_GQ : which == 1 ? H_GK : H_GV;
                        idx = base + (((size_t)b * Tc + t) * GEO_Hc + h) * (Nc * HDc)
                              + n * HDc + d;
                    } else {
                        int r2 = gc - 288;
                        int which = r2 >> 5, h = (r2 >> 4) & 1;
                        size_t base = which == 0 ? H_SQ : which == 1 ? H_SK : H_SV;
                        idx = base + (((size_t)b * Tc + t) * SEM_Hc + h) * (Nc * HDc)
                              + n * HDc + d;
                    }
                    hb[idx] = f2b(v);
                }
            }
        }
    }
}

// ---- kernel: pattern-q GEMM + pattern attention fused into geo_k ----------
__global__ __launch_bounds__(256, 2) void k_projp(
    const float* __restrict__ xp, const float* __restrict__ pat_qw,
    const float* __restrict__ pat_qb, const float* __restrict__ fws,
    bf16* __restrict__ hb) {
    __shared__ float xs[64 * 132];
    __shared__ float wsh[64 * 68];
    __shared__ float pks[1024], pvs[1024], pqbs[64];

    int tid = threadIdx.x;
    int tok0 = blockIdx.x * 64;
    int ty = tid >> 4, tx = tid & 15;

    for (int u = tid; u < 2048; u += 256) {
        int row = u >> 5, f4 = u & 31;
        *(float4*)&xs[row * 132 + f4 * 4] =
            *(const float4*)(xp + (size_t)(tok0 + row) * 128 + f4 * 4);
    }
    for (int u = tid; u < 1024; u += 256) {
        pks[u] = fws[F_PK + u];
        pvs[u] = fws[F_PV + u];
    }
    if (tid < 64) pqbs[tid] = pat_qb[tid];

    float acc[4][4] = {};
    for (int kh = 0; kh < 2; ++kh) {
        __syncthreads();
        for (int u = tid; u < 1024; u += 256) {
            int row = u >> 4, f4 = u & 15;
            *(float4*)&wsh[row * 68 + f4 * 4] =
                *(const float4*)(pat_qw + (size_t)row * 128 + kh * 64 + f4 * 4);
        }
        __syncthreads();
#pragma unroll 4
        for (int kk = 0; kk < 64; kk += 4) {
            float4 a[4], b[4];
#pragma unroll
            for (int i = 0; i < 4; ++i)
                a[i] = *(const float4*)&xs[(ty + 16 * i) * 132 + kh * 64 + kk];
#pragma unroll
            for (int j = 0; j < 4; ++j)
                b[j] = *(const float4*)&wsh[(tx + 16 * j) * 68 + kk];
#pragma unroll
            for (int i = 0; i < 4; ++i)
#pragma unroll
                for (int j = 0; j < 4; ++j) {
                    acc[i][j] = fmaf(a[i].x, b[j].x, acc[i][j]);
                    acc[i][j] = fmaf(a[i].y, b[j].y, acc[i][j]);
                    acc[i][j] = fmaf(a[i].z, b[j].z, acc[i][j]);
                    acc[i][j] = fmaf(a[i].w, b[j].w, acc[i][j]);
                }
        }
    }
    __syncthreads();
    float* pqs = xs;    // reuse
    float* plogs = wsh; // reuse
#pragma unroll
    for (int i = 0; i < 4; ++i)
#pragma unroll
        for (int j = 0; j < 4; ++j)
            pqs[(ty + 16 * i) * 68 + tx + 16 * j] = acc[i][j] + pqbs[tx + 16 * j];
    __syncthreads();
    {
        int tok = tid >> 2, k4 = (tid & 3) * 4;
        for (int k = k4; k < k4 + 4; ++k) {
            float s = 0.f;
#pragma unroll 16
            for (int e = 0; e < 64; ++e)
                s = fmaf(pqs[tok * 68 + e], pks[k * 64 + e], s);
            plogs[tok * 17 + k] = s * SCALEc;
        }
    }
    __syncthreads();
    {
        int tok = tid >> 2, q = tid & 3;
        float mx = -1e30f;
        for (int k = 0; k < 16; ++k) mx = fmaxf(mx, plogs[tok * 17 + k]);
        float p[16], sum = 0.f;
        for (int k = 0; k < 16; ++k) {
            p[k] = __expf(plogs[tok * 17 + k] - mx);
            sum += p[k];
        }
        float inv = 1.f / sum;
        int token = tok0 + tok;
        int b = token / (Tc * Nc);
        int rr = token - b * Tc * Nc;
        int t = rr >> 9;
        int n = rr & 511;
        for (int cc = 0; cc < 16; ++cc) {
            int c = q * 16 + cc;
            float v = 0.f;
            for (int k = 0; k < 16; ++k) v = fmaf(p[k], pvs[k * 64 + c], v);
            v *= inv;
            size_t idx = H_GK + (((size_t)b * Tc + t) * GEO_Hc + (c >> 4)) * (Nc * HDc)
                         + n * HDc + (c & 15);
            hb[idx] = f2b(b2f(hb[idx]) + v);
        }
    }
}

// ---- kernel: temporal attention (T=12 per node/head) ----------------------
__global__ __launch_bounds__(64) void k_tattn(bf16* __restrict__ hb) {
    int blk = blockIdx.x;
    int h = blk & 1;
    int bn = blk >> 1;
    int b = bn >> 9;
    int n = bn & 511;
    size_t base = ((size_t)(b * Nc + n) * T_Hc + h) * (Tc * HDc);

    __shared__ float q[192], kk[192], v[192], s[144];
    int tid = threadIdx.x;
    for (int u = tid; u < 192; u += 64) {
        q[u] = b2f(hb[H_TQ + base + u]);
        kk[u] = b2f(hb[H_TK + base + u]);
        v[u] = b2f(hb[H_TV + base + u]);
    }
    __syncthreads();
    for (int idx = tid; idx < 144; idx += 64) {
        int qi = idx / 12, ki = idx - qi * 12;
        float acc = 0.f;
#pragma unroll
        for (int d = 0; d < 16; ++d) acc = fmaf(q[qi * 16 + d], kk[ki * 16 + d], acc);
        s[idx] = acc * SCALEc;
    }
    __syncthreads();
    if (tid < 12) {
        float mx = -1e30f;
        for (int ki = 0; ki < 12; ++ki) mx = fmaxf(mx, s[tid * 12 + ki]);
        float sum = 0.f;
        for (int ki = 0; ki < 12; ++ki) {
            float p = __expf(s[tid * 12 + ki] - mx);
            s[tid * 12 + ki] = p;
            sum += p;
        }
        float inv = 1.f / sum;
        for (int ki = 0; ki < 12; ++ki) s[tid * 12 + ki] *= inv;
    }
    __syncthreads();
    for (int idx = tid; idx < 192; idx += 64) {
        int qi = idx >> 4, d = idx & 15;
        float acc = 0.f;
#pragma unroll
        for (int ki = 0; ki < 12; ++ki) acc = fmaf(s[qi * 12 + ki], v[ki * 16 + d], acc);
        hb[H_CC + (((size_t)b * Tc + qi) * Nc + n) * Dc + h * HDc + d] = f2b(acc);
    }
}

// ---- kernel: MFMA spatial attention (geo & sem), S^T formulation ----------
__global__ __launch_bounds__(256, 4) void k_attn2(
    bf16* __restrict__ hb, size_t QO, size_t KO, size_t VO, int H,
    const bf16* __restrict__ biasp, size_t bstride, int coff) {
    __shared__ short vt[16 * 512];       // V^T, row d, swizzled granules
    __shared__ short pbuf[4][16 * 128];  // per-wave P chunk, row q, swizzled
    __shared__ float lt[4][16];
    __shared__ float at[4][16];

    int bid = blockIdx.x;
    int part = bid & 3;
    int bth_lin = bid >> 2;
    int h = bth_lin % H;
    int rest = bth_lin / H;
    int t = rest % Tc;
    int b = rest / Tc;

    size_t bth = (((size_t)b * Tc + t) * H + h) * (size_t)(Nc * HDc);
    const bf16* Qp = hb + QO + bth;
    const bf16* Kp = hb + KO + bth;
    const bf16* Vp = hb + VO + bth;
    const bf16* bp = biasp + (size_t)b * bstride;

    int tid = threadIdx.x;
    int w = tid >> 6;
    int lane = tid & 63;
    int l15 = lane & 15;
    int quad = lane >> 4;

    for (int idx = tid; idx < 8192; idx += 256) {
        int k = idx >> 4, d = idx & 15;
        int kk = ((((k >> 3) & 7) ^ (d & 7)) << 3) | (k & ~63) | (k & 7);
        vt[d * 512 + kk] = *reinterpret_cast<const short*>(Vp + idx);
    }
    __syncthreads();

    short* pw = &pbuf[w][0];
    float* lw = lt[w];
    float* aw = at[w];
    int sw = l15 & 7;

    for (int qq = 0; qq < 2; ++qq) {
        int q0 = part * 128 + w * 32 + qq * 16;
        int qg = q0 + l15;
        short8 bq = {0, 0, 0, 0, 0, 0, 0, 0};
        if (quad < 2) bq = *(const short8*)(Qp + (size_t)qg * 16 + quad * 8);

        float m_i = -3e38f, l_i = 0.f;
        f32x4 O = {0.f, 0.f, 0.f, 0.f};

        for (int ch = 0; ch < 4; ++ch) {
            int kabs0 = ch * 128;
            f32x4 S[8];
#pragma unroll
            for (int kt = 0; kt < 8; ++kt) {
                int kabs = kabs0 + kt * 16;
                short4 bb = *(const short4*)(bp + (size_t)qg * 512 + kabs + quad * 4);
                f32x4 c;
                c[0] = bs2f(bb.x); c[1] = bs2f(bb.y);
                c[2] = bs2f(bb.z); c[3] = bs2f(bb.w);
                short8 ak = {0, 0, 0, 0, 0, 0, 0, 0};
                if (quad < 2)
                    ak = *(const short8*)(Kp + (size_t)(kabs + l15) * 16 + quad * 8);
                S[kt] = __builtin_amdgcn_mfma_f32_16x16x32_bf16(ak, bq, c, 0, 0, 0);
            }
            float cm = S[0][0];
#pragma unroll
            for (int kt = 0; kt < 8; ++kt)
#pragma unroll
                for (int r = 0; r < 4; ++r) cm = fmaxf(cm, S[kt][r]);
            cm = fmaxf(cm, __shfl_xor(cm, 16));
            cm = fmaxf(cm, __shfl_xor(cm, 32));
            float mnew = fmaxf(m_i, cm);
            float alpha = __expf(m_i - mnew);
            m_i = mnew;
            float psum = 0.f;
#pragma unroll
            for (int kt = 0; kt < 8; ++kt) {
#pragma unroll
                for (int r = 0; r < 4; ++r) {
                    float p = __expf(S[kt][r] - mnew);
                    S[kt][r] = p;
                    psum += p;
                }
            }
            psum += __shfl_xor(psum, 16);
            psum += __shfl_xor(psum, 32);
            l_i = l_i * alpha + psum;
            if (quad == 0) aw[l15] = alpha;
#pragma unroll
            for (int kt = 0; kt < 8; ++kt) {
                short4 pk4;
                pk4.x = f2bs(S[kt][0]); pk4.y = f2bs(S[kt][1]);
                pk4.z = f2bs(S[kt][2]); pk4.w = f2bs(S[kt][3]);
                int g = 2 * kt + (quad >> 1);
                *(short4*)&pw[l15 * 128 + ((g ^ sw) << 3) + ((quad & 1) << 2)] = pk4;
            }
            float4 a4 = *(float4*)&aw[quad * 4];
            O[0] *= a4.x; O[1] *= a4.y; O[2] *= a4.z; O[3] *= a4.w;
#pragma unroll
            for (int kw = 0; kw < 4; ++kw) {
                int g = 4 * kw + quad;
                short8 ap = *(const short8*)&pw[l15 * 128 + ((g ^ sw) << 3)];
                short8 bv = *(const short8*)&vt[l15 * 512 + kabs0 + ((g ^ sw) << 3)];
                O = __builtin_amdgcn_mfma_f32_16x16x32_bf16(ap, bv, O, 0, 0, 0);
            }
        }
        if (quad == 0) lw[l15] = l_i;
        float4 l4 = *(float4*)&lw[quad * 4];
        float inv0 = 1.f / l4.x, inv1 = 1.f / l4.y, inv2 = 1.f / l4.z, inv3 = 1.f / l4.w;
        size_t obase = H_CC + (((size_t)b * Tc + t) * Nc + q0) * Dc + coff + h * HDc + l15;
        hb[obase + (size_t)(quad * 4 + 0) * Dc] = f2b(O[0] * inv0);
        hb[obase + (size_t)(quad * 4 + 1) * Dc] = f2b(O[1] * inv1);
        hb[obase + (size_t)(quad * 4 + 2) * Dc] = f2b(O[2] * inv2);
        hb[obase + (size_t)(quad * 4 + 3) * Dc] = f2b(O[3] * inv3);
    }
}

// ---- kernel: MFMA output projection CC(49152x128) @ proj_w^T --------------
__global__ __launch_bounds__(256, 3) void k_outm(
    const bf16* __restrict__ hb, const float* __restrict__ proj_b,
    float* __restrict__ out) {
    __shared__ short cs[128 * 128];   // 32 KB, swizzled granules
    __shared__ float pbs[128];

    int tid = threadIdx.x;
    int m0 = blockIdx.x * 128;

    for (int u = tid; u < 2048; u += 256) {
        int row = u >> 4, g = u & 15;
        *(short8*)&cs[row * 128 + ((g ^ (row & 7)) << 3)] =
            *(const short8*)(hb + H_CC + (size_t)(m0 + row) * 128 + g * 8);
    }
    if (tid < 128) pbs[tid] = proj_b[tid];
    __syncthreads();

    int w = tid >> 6;
    int lane = tid & 63;
    int l15 = lane & 15;
    int quad = lane >> 4;
    const bf16* w2o = hb + H_W2O;

    f32x4 acc[2][8];
#pragma unroll
    for (int i = 0; i < 2; ++i)
#pragma unroll
        for (int j = 0; j < 8; ++j) acc[i][j] = (f32x4){0.f, 0.f, 0.f, 0.f};

#pragma unroll
    for (int ks = 0; ks < 4; ++ks) {
        int r0 = w * 32 + l15;
        int r1 = r0 + 16;
        short8 a0 = *(const short8*)&cs[r0 * 128 + (((ks * 4 + quad) ^ (r0 & 7)) << 3)];
        short8 a1 = *(const short8*)&cs[r1 * 128 + (((ks * 4 + quad) ^ (r1 & 7)) << 3)];
#pragma unroll
        for (int nj = 0; nj < 8; ++nj) {
            short8 bfr = *(const short8*)(w2o + (size_t)(nj * 16 + l15) * 128
                                          + ks * 32 + quad * 8);
            acc[0][nj] = __builtin_amdgcn_mfma_f32_16x16x32_bf16(a0, bfr, acc[0][nj], 0, 0, 0);
            acc[1][nj] = __builtin_amdgcn_mfma_f32_16x16x32_bf16(a1, bfr, acc[1][nj], 0, 0, 0);
        }
    }
#pragma unroll
    for (int i = 0; i < 2; ++i) {
#pragma unroll
        for (int nj = 0; nj < 8; ++nj) {
            int ch = nj * 16 + l15;
            float bias = pbs[ch];
#pragma unroll
            for (int r = 0; r < 4; ++r) {
                int token = m0 + w * 32 + i * 16 + quad * 4 + r;
                out[(size_t)token * 128 + ch] = acc[i][nj][r] + bias;
            }
        }
    }
}

extern "C" void kernel_launch(void* const* d_in, const int* in_sizes, int n_in,
                              void* d_out, int out_size, void* d_ws, size_t ws_size,
                              hipStream_t stream) {
    const float* x = (const float*)d_in[0];
    const float* xp = (const float*)d_in[1];
    const float* pattern_keys = (const float*)d_in[2];
    const float* dyn = (const float*)d_in[3];
    const void* geo_mask = d_in[4];
    const void* sem_mask = d_in[5];
    const float* t_qw = (const float*)d_in[6];
    const float* t_kw = (const float*)d_in[7];
    const float* t_vw = (const float*)d_in[8];
    const float* geo_qw = (const float*)d_in[9];
    const float* geo_kw = (const float*)d_in[10];
    const float* geo_vw = (const float*)d_in[11];
    const float* sem_qw = (const float*)d_in[12];
    const float* sem_kw = (const float*)d_in[13];
    const float* sem_vw = (const float*)d_in[14];
    const float* pat_qw = (const float*)d_in[15];
    const float* pat_qb = (const float*)d_in[16];
    const float* pat_kw = (const float*)d_in[17];
    const float* pat_kb = (const float*)d_in[18];
    const float* pat_vw = (const float*)d_in[19];
    const float* pat_vb = (const float*)d_in[20];
    const float* proj_w = (const float*)d_in[21];
    const float* proj_b = (const float*)d_in[22];

    bf16* hb = (bf16*)d_ws;
    float* fws = (float*)d_ws;

    k_prep<<<8, 256, 0, stream>>>(pattern_keys, pat_kw, pat_kb, pat_vw, pat_vb, fws);
    k_maskdet<<<1, 256, 0, stream>>>((const unsigned char*)geo_mask, fws);
    k_wcvt<<<256, 256, 0, stream>>>(t_qw, t_kw, t_vw, geo_qw, geo_kw, geo_vw,
                                    sem_qw, sem_kw, sem_vw, proj_w, hb);
    k_projx<<<384, 256, 0, stream>>>(x, hb);
    k_projp<<<768, 256, 0, stream>>>(xp, pat_qw, pat_qb, fws, hb);
    k_tattn<<<Bc * Nc * T_Hc, 64, 0, stream>>>(hb);
    k_bias<<<9216, 256, 0, stream>>>(dyn, (const unsigned char*)geo_mask,
                                     (const unsigned char*)sem_mask, fws, hb);
    k_attn2<<<Bc * Tc * GEO_Hc * 4, 256, 0, stream>>>(
        hb, H_GQ, H_GK, H_GV, GEO_Hc, hb + H_BG, (size_t)Nc * Nc, 32);
    k_attn2<<<Bc * Tc * SEM_Hc * 4, 256, 0, stream>>>(
        hb, H_SQ, H_SK, H_SV, SEM_Hc, hb + H_BS, 0, 96);
    k_outm<<<384, 256, 0, stream>>>(hb, proj_b, (float*)d_out);
}